// Round 4
// baseline (2177.758 us; speedup 1.0000x reference)
//
#include <hip/hip_runtime.h>
#include <hip/hip_bf16.h>
#include <stdint.h>

// HMM batched forward, B=128, T=8192, S=65 (state 0 = bookend dead after init), V=1024.
//
// R4: R3 post-mortem showed the compiler sinks register-prefetch loads to their use
// (VGPR_Count=132 can't hold a depth-4 ring), leaving ~600 cyc/app of exposed fetch
// latency. Fix: prefetch via __builtin_amdgcn_global_load_lds into a depth-4 LDS slot
// ring (4 DISTINCT __shared__ objects -> precise alias-based waits), manual
// s_waitcnt vmcnt(27) per phase (exactly 9 DMAs/app: 8x16B table + 1x4B emission).
// Hot loop has NO other VMEM: obs staged as u16 pairs in LDS; per-app slog gather
// eliminated (sum_a slog[v1_a] is separable -> folded into the staging loop).
// Tables stored in two pre-swizzled global copies (E/O parity layouts) so DMAs are
// contiguous 1KB wave-reads and slot ds_read_b128s are conflict-free sequential.

#define HMM_B 128
#define HMM_T 8192
#define HMM_S 65
#define HMM_V 1024
#define LN2 0.6931471805599453

typedef __fp16 v2h __attribute__((ext_vector_type(2)));
typedef unsigned int uint;

// ---------------- device-global tables ----------------
__device__ __attribute__((aligned(16))) __fp16 gMtabE[HMM_V * 4096];  // even-app layout
__device__ __attribute__((aligned(16))) __fp16 gMtabO[HMM_V * 4096];  // odd-app layout
__device__ __attribute__((aligned(16))) __fp16 gP1E[4096];            // app-0 1-step, E layout
__device__ __attribute__((aligned(16))) float  gEmitT[HMM_V * 64];    // exp emissions [v][j]
__device__ float gSlog[HMM_V];   // per-v table scale correction (nats)
__device__ float gET[64 * 64];   // exp transitions, live states [i][j]
__device__ __attribute__((aligned(16))) float gArow0[64];
__device__ __attribute__((aligned(16))) float gTcs[64];  // exp(tcol - tcmax)
__device__ float gTcmax;

// original blocked f16 layout (as R3): entry (i,m) -> flat f16 index
__device__ __forceinline__ int blk_f(int i, int m) {
    return (((i >> 3) * 8 + (m >> 3)) * 64) + (((i & 7) >> 1) * 16) + ((m & 7) * 2) + (i & 1);
}
// DMA-swizzled layouts: instruction r deposits LDS int4s [r*64+lane] <- global [r*64+lane].
// Lane i needs block bE(i)=(i&7)*8+(i>>3) (even apps) / bO(i)=i (odd apps), int4 r.
__device__ __forceinline__ int e_pos(int F) {  // blocked f16 idx -> E-copy f16 idx
    int f = F >> 3, sub = F & 7;
    int r = f & 7, b = f >> 3;
    int iE = ((b & 7) << 3) | (b >> 3);
    return (r * 64 + iE) * 8 + sub;
}
__device__ __forceinline__ int o_pos(int F) {
    int f = F >> 3, sub = F & 7;
    int r = f & 7, b = f >> 3;
    return (r * 64 + b) * 8 + sub;
}

// ---------------- helpers ----------------
__device__ __forceinline__ float fdot2_(v2h a, v2h b, float c) {
#if __has_builtin(__builtin_amdgcn_fdot2)
    return __builtin_amdgcn_fdot2(a, b, c, false);
#else
    return c + (float)a.x * (float)b.x + (float)a.y * (float)b.y;
#endif
}

template <int CTRL>
__device__ __forceinline__ float dpp_add(float x) {
    // 0xB1=quad_perm xor1, 0x4E=quad_perm xor2, 0x141=row_half_mirror
    return x + __int_as_float(__builtin_amdgcn_update_dpp(
                   0, __float_as_int(x), CTRL, 0xF, 0xF, true));
}

__device__ __forceinline__ v2h as_v2h(int x) { return __builtin_bit_cast(v2h, x); }

typedef __attribute__((address_space(1))) void as1v;
typedef __attribute__((address_space(3))) void as3v;
__device__ __forceinline__ void gld16(const void* g, void* l) {
    __builtin_amdgcn_global_load_lds((as1v*)g, (as3v*)l, 16, 0, 0);
}
__device__ __forceinline__ void gld4(const void* g, void* l) {
    __builtin_amdgcn_global_load_lds((as1v*)g, (as3v*)l, 4, 0, 0);
}

#define WAITP asm volatile("s_waitcnt vmcnt(27)" ::: "memory");

#define RED_LOW_ALL(r)                      \
    _Pragma("unroll")                       \
    for (int m_ = 0; m_ < 8; ++m_) {        \
        r[m_] = dpp_add<0xB1>(r[m_]);       \
        r[m_] = dpp_add<0x4E>(r[m_]);       \
        r[m_] = dpp_add<0x141>(r[m_]);      \
    }

#define RED_HIGH_ALL(r)                     \
    _Pragma("unroll")                       \
    for (int m_ = 0; m_ < 8; ++m_) {        \
        r[m_] += __shfl_xor(r[m_], 8);      \
        r[m_] += __shfl_xor(r[m_], 16);     \
        r[m_] += __shfl_xor(r[m_], 32);     \
    }

// issue the 9 DMAs for one app: 8x16B table rows + 1x4B-per-lane emission row
#define ISSUE_PREFETCH(W, DSTSLOT, GTAB)                                        \
    {                                                                           \
        uint w_ = (W);                                                          \
        uint v1_ = w_ & 0xFFFFu, v2_ = w_ >> 16;                                \
        const char* ts_ = (const char*)(GTAB) + v1_ * 8192u + lane * 16u;       \
        char* td_ = (char*)(DSTSLOT);                                           \
        _Pragma("unroll")                                                       \
        for (int r_ = 0; r_ < 8; ++r_)                                          \
            gld16(ts_ + r_ * 1024, td_ + r_ * 1024);                            \
        gld4((const char*)gEmitT + v2_ * 256u + lane * 4u, td_ + 8192);         \
    }

// one application from LDS slot; MAIN_LOW: even apps reduce over low lane bits
#define COMPUTE_APP2(SLOT, EB, MAIN_LOW)                                              \
    {                                                                                 \
        const int4* tp_ = (const int4*)(SLOT);                                        \
        int4 T_[8];                                                                   \
        _Pragma("unroll")                                                             \
        for (int r_ = 0; r_ < 8; ++r_) T_[r_] = tp_[r_ * 64 + lane];                  \
        const int* tb_ = (const int*)T_;                                              \
        const float4* ef_ = (const float4*)((const char*)(SLOT) + 8192);              \
        float4 E0_ = ef_[EB];                                                         \
        float4 E1_ = ef_[(EB) + 1];                                                   \
        v2h ap0_ = __builtin_amdgcn_cvt_pkrtz(ab[0], ab[1]);                          \
        v2h ap1_ = __builtin_amdgcn_cvt_pkrtz(ab[2], ab[3]);                          \
        v2h ap2_ = __builtin_amdgcn_cvt_pkrtz(ab[4], ab[5]);                          \
        v2h ap3_ = __builtin_amdgcn_cvt_pkrtz(ab[6], ab[7]);                          \
        float r_a[8];                                                                 \
        _Pragma("unroll")                                                             \
        for (int m_ = 0; m_ < 8; ++m_) {                                              \
            float acc_ = fdot2_(ap0_, as_v2h(tb_[m_]), 0.0f);                         \
            acc_ = fdot2_(ap1_, as_v2h(tb_[8 + m_]), acc_);                           \
            acc_ = fdot2_(ap2_, as_v2h(tb_[16 + m_]), acc_);                          \
            acc_ = fdot2_(ap3_, as_v2h(tb_[24 + m_]), acc_);                          \
            r_a[m_] = acc_;                                                           \
        }                                                                             \
        if (MAIN_LOW) { RED_LOW_ALL(r_a) } else { RED_HIGH_ALL(r_a) }                 \
        r_a[0] *= E0_.x; r_a[1] *= E0_.y; r_a[2] *= E0_.z; r_a[3] *= E0_.w;           \
        r_a[4] *= E1_.x; r_a[5] *= E1_.y; r_a[6] *= E1_.z; r_a[7] *= E1_.w;           \
        float s_ = ((r_a[0] + r_a[1]) + (r_a[2] + r_a[3])) +                          \
                   ((r_a[4] + r_a[5]) + (r_a[6] + r_a[7]));                           \
        if (MAIN_LOW) {                                                               \
            s_ += __shfl_xor(s_, 8); s_ += __shfl_xor(s_, 16); s_ += __shfl_xor(s_, 32); \
        } else {                                                                      \
            s_ = dpp_add<0xB1>(s_); s_ = dpp_add<0x4E>(s_); s_ = dpp_add<0x141>(s_);  \
        }                                                                             \
        int e_;                                                                       \
        (void)frexpf(s_, &e_);                                                        \
        eacc += e_;                                                                   \
        int me_ = -e_;                                                                \
        _Pragma("unroll")                                                             \
        for (int m_ = 0; m_ < 8; ++m_) ab[m_] = ldexpf(r_a[m_], me_);                 \
    }

// ---------------- prep kernels ----------------
__global__ __launch_bounds__(256) void prep_emit(const float* __restrict__ log_emit) {
    int idx = blockIdx.x * 256 + threadIdx.x;  // 0..65535
    int v = idx >> 6;
    int j = idx & 63;
    gEmitT[idx] = expf(log_emit[(j + 1) * HMM_V + v]);
}

__global__ __launch_bounds__(64) void prep_small(const float* __restrict__ log_trans,
                                                 const float* __restrict__ log_pi) {
    int j = threadIdx.x;  // live state j+1
    for (int i = 0; i < 64; ++i)
        gET[i * 64 + j] = expf(log_trans[(i + 1) * HMM_S + (j + 1)]);
    float s = 0.f;
    for (int i = 0; i < HMM_S; ++i)
        s += expf(log_pi[i]) * expf(log_trans[i * HMM_S + (j + 1)]);
    gArow0[j] = s;
    float tc = log_trans[(j + 1) * HMM_S + 0];
    float mx = tc;
    for (int d = 1; d < 64; d <<= 1) mx = fmaxf(mx, __shfl_xor(mx, d));
    gTcs[j] = expf(tc - mx);
    if (j == 0) gTcmax = mx;
    for (int i = 0; i < 64; ++i) {
        int F = blk_f(i, j);
        gP1E[e_pos(F)] = (__fp16)gET[i * 64 + j];
    }
}

__global__ __launch_bounds__(64) void prep_table() {
    __shared__ float ETs[64 * 64];  // [i][j]
    __shared__ float ETp[64 * 66];  // [j][m], padded
    __shared__ float ev[64];
    const int m = threadIdx.x;
    const int v = blockIdx.x;
    for (int i = 0; i < 64; ++i) ETs[i * 64 + m] = gET[i * 64 + m];
    for (int j = 0; j < 64; ++j) ETp[j * 66 + m] = gET[j * 64 + m];
    ev[m] = gEmitT[v * 64 + m];
    __syncthreads();
    float acc[64];
#pragma unroll
    for (int i = 0; i < 64; ++i) acc[i] = 0.f;
    for (int j = 0; j < 64; ++j) {
        float w = ev[j] * ETp[j * 66 + m];
#pragma unroll
        for (int i = 0; i < 64; ++i) acc[i] = fmaf(ETs[i * 64 + j], w, acc[i]);
    }
    float mx = acc[0];
#pragma unroll
    for (int i = 1; i < 64; ++i) mx = fmaxf(mx, acc[i]);
    for (int d = 1; d < 64; d <<= 1) mx = fmaxf(mx, __shfl_xor(mx, d));
    int e;
    (void)frexpf(mx, &e);
    float sc = exp2f((float)(11 - e));
    if (m == 0) gSlog[v] = (float)(e - 11) * (float)LN2;
    for (int i = 0; i < 64; ++i) {
        __fp16 hv = (__fp16)(acc[i] * sc);
        int F = blk_f(i, m);
        gMtabE[v * 4096 + e_pos(F)] = hv;
        gMtabO[v * 4096 + o_pos(F)] = hv;
    }
}

// ---------------- main serial-scan kernel: 1 wave per batch ----------------
__global__ __launch_bounds__(64, 1) void hmm_fwd(const int* __restrict__ obvs,
                                                 float* __restrict__ out) {
    // 4 DISTINCT slot objects (precise LDS-DMA alias tracking); 528 int4 = 8KB tab + 256B em
    __shared__ __attribute__((aligned(16))) int4 slot0[528];
    __shared__ __attribute__((aligned(16))) int4 slot1[528];
    __shared__ __attribute__((aligned(16))) int4 slot2[528];
    __shared__ __attribute__((aligned(16))) int4 slot3[528];
    __shared__ __attribute__((aligned(16))) unsigned short obs_w16[HMM_T + 32];  // u16 obs + pad
    __shared__ float a0lds[64];

    const int b = blockIdx.x;
    const int lane = threadIdx.x;

    // ---- stage obs as u16 + gather separable slog sum (off the serial chain) ----
    float slsum = 0.f;
    {
        const int4* og = (const int4*)(obvs + b * HMM_T);
        ushort4* ow = (ushort4*)obs_w16;
        for (int it = lane; it < HMM_T / 4; it += 64) {
            int4 o = og[it];
            ow[it] = make_ushort4((unsigned short)o.x, (unsigned short)o.y,
                                  (unsigned short)o.z, (unsigned short)o.w);
            // v1 indices are obs[2a], a=1..4095 <=> even flat idx n=4it(+2), n>=2
            float sx = gSlog[o.x];
            float sz = gSlog[o.z];
            slsum += (it != 0 ? sx : 0.f) + sz;
        }
        if (lane < 8) ow[HMM_T / 4 + lane] = make_ushort4(0, 0, 0, 0);
    }

    // ---- init t=0 (exact: includes bookend state) ----
    int o0 = obvs[b * HMM_T];
    float a0 = gArow0[lane] * gEmitT[o0 * 64 + lane];
    a0lds[lane] = a0;
    __syncthreads();  // orders staging + a0 handoff; drains vmcnt BEFORE any DMA

    float ab[8];
#pragma unroll
    for (int k = 0; k < 8; ++k) ab[k] = a0lds[(lane & 7) * 8 + k];  // ab[k]=alpha[8l+k]

    const uint* obs_w32 = (const uint*)obs_w16;  // word a = (obs[2a], obs[2a+1])
    const int ebE = (lane >> 3) * 2;
    const int ebO = (lane & 7) * 2;

    int eacc = 0;

    // ---- prologue: DMA apps 0 (P1E), 1 (O), 2 (E) -> 27 outstanding ----
    {
        const char* p1 = (const char*)gP1E + lane * 16;
        char* d0 = (char*)slot0;
#pragma unroll
        for (int r = 0; r < 8; ++r) gld16(p1 + r * 1024, d0 + r * 1024);
        uint w0 = obs_w32[0];
        gld4((const char*)gEmitT + (w0 >> 16) * 256 + lane * 4, d0 + 8192);
    }
    ISSUE_PREFETCH(obs_w32[1], slot1, gMtabO)
    ISSUE_PREFETCH(obs_w32[2], slot2, gMtabE)
    uint obp0 = obs_w32[3], obp1 = obs_w32[4], obp2 = obs_w32[5], obp3 = obs_w32[6];

    // ---- main loop: 1024 groups x 4 apps; issue-9 -> wait vmcnt(27) -> compute ----
    for (int g = 0; g < 1024; ++g) {
        const int base = 4 * g;
        // phase 0: compute app base (even, slot0); prefetch base+3 (odd) -> slot3
        ISSUE_PREFETCH(obp0, slot3, gMtabO)
        obp0 = obs_w32[base + 7];
        WAITP
        COMPUTE_APP2(slot0, ebE, true)
        // phase 1: compute base+1 (odd, slot1); prefetch base+4 (even) -> slot0
        ISSUE_PREFETCH(obp1, slot0, gMtabE)
        obp1 = obs_w32[base + 8];
        WAITP
        COMPUTE_APP2(slot1, ebO, false)
        // phase 2: compute base+2 (even, slot2); prefetch base+5 (odd) -> slot1
        ISSUE_PREFETCH(obp2, slot1, gMtabO)
        obp2 = obs_w32[base + 9];
        WAITP
        COMPUTE_APP2(slot2, ebE, true)
        // phase 3: compute base+3 (odd, slot3); prefetch base+6 (even) -> slot2
        ISSUE_PREFETCH(obp3, slot2, gMtabE)
        obp3 = obs_w32[base + 10];
        WAITP
        COMPUTE_APP2(slot3, ebO, false)
    }

    // ---- termination (last app odd): ab[m] = alpha[8l+m] ----
    float t = 0.f;
#pragma unroll
    for (int m = 0; m < 8; ++m) t += ab[m] * gTcs[(lane & 7) * 8 + m];
    t = dpp_add<0xB1>(t);
    t = dpp_add<0x4E>(t);
    t = dpp_add<0x141>(t);
#pragma unroll
    for (int d = 1; d < 64; d <<= 1) slsum += __shfl_xor(slsum, d);
    if (lane == 0)
        out[b] = (float)((double)slsum + (double)eacc * LN2 + (double)gTcmax +
                         (double)__logf(t));
}

// ---------------- launch ----------------
extern "C" void kernel_launch(void* const* d_in, const int* in_sizes, int n_in,
                              void* d_out, int out_size, void* d_ws, size_t ws_size,
                              hipStream_t stream) {
    const float* log_trans = (const float*)d_in[0];  // 65*65
    const float* log_emit  = (const float*)d_in[1];  // 65*1024
    const float* log_pi    = (const float*)d_in[2];  // 65
    const int*   obvs      = (const int*)d_in[3];    // 128*8192
    float* out = (float*)d_out;

    prep_emit<<<256, 256, 0, stream>>>(log_emit);
    prep_small<<<1, 64, 0, stream>>>(log_trans, log_pi);
    prep_table<<<1024, 64, 0, stream>>>();
    hmm_fwd<<<HMM_B, 64, 0, stream>>>(obvs, out);
}

// Round 5
// 1427.932 us; speedup vs baseline: 1.5251x; 1.5251x over previous
//
#include <hip/hip_runtime.h>
#include <hip/hip_bf16.h>
#include <stdint.h>

// HMM batched forward, B=128, T=8192, S=65 (state 0 = bookend dead after init), V=1024.
//
// R5: deterministic register prefetch pipeline via inline asm.
// R3 failed (compiler sank HIP prefetch loads to use, depth-1 effective);
// R4 failed (compiler inserts its own conservative waits before reading
// global_load_lds-written LDS slots, plus 2x table copies halved L2 hit).
// Fix: per app ONE asm block of exactly 10 global_load_dwordx4 (8 table +
// 2 emission) into explicitly-held VGPRs; depth-4 ring; steady state
// s_waitcnt vmcnt(30) with 40 outstanding drains exactly the app about to
// be computed; the waitcnt asm ties ("+v") all 10 destination quads so
// consumers cannot be scheduled above it. No other VMEM in the loop
// (obs as u16 in LDS, slog separable-summed at staging, pow2 renorm).
// Single 8MB table (R3 layout) for best L2 residency.

#define HMM_B 128
#define HMM_T 8192
#define HMM_S 65
#define HMM_V 1024
#define LN2 0.6931471805599453

typedef __fp16 v2h __attribute__((ext_vector_type(2)));
typedef int    v4i __attribute__((ext_vector_type(4)));
typedef float  v4f __attribute__((ext_vector_type(4)));
typedef unsigned int uint;

// ---------------- device-global tables ----------------
__device__ __attribute__((aligned(16))) __fp16 gMtab[HMM_V * 4096]; // blocked 2-step tables
__device__ __attribute__((aligned(16))) __fp16 gP1[4096];           // blocked 1-step table
__device__ __attribute__((aligned(16))) float  gEmitT[HMM_V * 64];  // exp emissions [v][j]
__device__ float gSlog[HMM_V];   // per-v table scale correction (nats)
__device__ float gET[64 * 64];   // exp transitions, live states [i][j]
__device__ __attribute__((aligned(16))) float gArow0[64];
__device__ __attribute__((aligned(16))) float gTcs[64];  // exp(tcol - tcmax)
__device__ float gTcmax;

// blocked f16 layout: entry (i,m) -> block (i>>3, m>>3) of 64 f16 (128 B contiguous),
// within-block pair-major for dot2: ((i&7)>>1)*16 + (m&7)*2 + (i&1)
__device__ __forceinline__ int blk_idx(int i, int m) {
    return (((i >> 3) * 8 + (m >> 3)) * 64) + (((i & 7) >> 1) * 16) + ((m & 7) * 2) + (i & 1);
}

// ---------------- helpers ----------------
__device__ __forceinline__ float fdot2_(v2h a, v2h b, float c) {
#if __has_builtin(__builtin_amdgcn_fdot2)
    return __builtin_amdgcn_fdot2(a, b, c, false);
#else
    return c + (float)a.x * (float)b.x + (float)a.y * (float)b.y;
#endif
}

template <int CTRL>
__device__ __forceinline__ float dpp_add(float x) {
    // 0xB1=quad_perm xor1, 0x4E=quad_perm xor2, 0x141=row_half_mirror
    return x + __int_as_float(__builtin_amdgcn_update_dpp(
                   0, __float_as_int(x), CTRL, 0xF, 0xF, true));
}

__device__ __forceinline__ v2h as_v2h(int x) { return __builtin_bit_cast(v2h, x); }

// issue exactly 10 global_load_dwordx4 for one app (8 table quads + 2 emission).
// Early-clobber outputs: async writeback must not alias the address operands.
#define ISSUE_APP(TQ, E0, E1, W, TBASE, BLKB, EBB)                                \
    {                                                                             \
        uint w_ = (W);                                                            \
        const char* tp_ = (const char*)(TBASE) + (w_ & 0xFFFFu) * 8192u + (BLKB); \
        const char* ep_ = (const char*)gEmitT + (w_ >> 16) * 256u + (EBB);        \
        asm volatile("global_load_dwordx4 %0, %10, off\n\t"                       \
                     "global_load_dwordx4 %1, %10, off offset:16\n\t"             \
                     "global_load_dwordx4 %2, %10, off offset:32\n\t"             \
                     "global_load_dwordx4 %3, %10, off offset:48\n\t"             \
                     "global_load_dwordx4 %4, %10, off offset:64\n\t"             \
                     "global_load_dwordx4 %5, %10, off offset:80\n\t"             \
                     "global_load_dwordx4 %6, %10, off offset:96\n\t"             \
                     "global_load_dwordx4 %7, %10, off offset:112\n\t"            \
                     "global_load_dwordx4 %8, %11, off\n\t"                       \
                     "global_load_dwordx4 %9, %11, off offset:16"                 \
                     : "=&v"(TQ[0]), "=&v"(TQ[1]), "=&v"(TQ[2]), "=&v"(TQ[3]),    \
                       "=&v"(TQ[4]), "=&v"(TQ[5]), "=&v"(TQ[6]), "=&v"(TQ[7]),    \
                       "=&v"(E0), "=&v"(E1)                                       \
                     : "v"(tp_), "v"(ep_)                                         \
                     : "memory");                                                 \
    }

// wait until only 30 VMEM outstanding (drains the oldest 10 = the app about to be
// computed), tying all destination regs so consumers stay below the wait.
#define WAIT_TIE(TQ, E0, E1)                                                      \
    asm volatile("s_waitcnt vmcnt(30)"                                            \
                 : "+v"(TQ[0]), "+v"(TQ[1]), "+v"(TQ[2]), "+v"(TQ[3]),            \
                   "+v"(TQ[4]), "+v"(TQ[5]), "+v"(TQ[6]), "+v"(TQ[7]),            \
                   "+v"(E0), "+v"(E1)                                             \
                 :: "memory")

#define RED_LOW_ALL(r)                      \
    _Pragma("unroll")                       \
    for (int m_ = 0; m_ < 8; ++m_) {        \
        r[m_] = dpp_add<0xB1>(r[m_]);       \
        r[m_] = dpp_add<0x4E>(r[m_]);       \
        r[m_] = dpp_add<0x141>(r[m_]);      \
    }

#define RED_HIGH_ALL(r)                     \
    _Pragma("unroll")                       \
    for (int m_ = 0; m_ < 8; ++m_) {        \
        r[m_] += __shfl_xor(r[m_], 8);      \
        r[m_] += __shfl_xor(r[m_], 16);     \
        r[m_] += __shfl_xor(r[m_], 32);     \
    }

// one application; table pair (p, col m) lives at TQ[2p + (m>>2)] component (m&3)
#define COMPUTE_APP(TQ, E0, E1, MAIN_LOW)                                         \
    {                                                                             \
        v2h ap0 = __builtin_amdgcn_cvt_pkrtz(ab[0], ab[1]);                       \
        v2h ap1 = __builtin_amdgcn_cvt_pkrtz(ab[2], ab[3]);                       \
        v2h ap2 = __builtin_amdgcn_cvt_pkrtz(ab[4], ab[5]);                       \
        v2h ap3 = __builtin_amdgcn_cvt_pkrtz(ab[6], ab[7]);                       \
        float r_a[8];                                                             \
        _Pragma("unroll")                                                         \
        for (int m_ = 0; m_ < 8; ++m_) {                                          \
            const int c_ = m_ & 3, rr_ = m_ >> 2;                                 \
            float acc_ = fdot2_(ap0, as_v2h(TQ[0 + rr_][c_]), 0.0f);              \
            acc_ = fdot2_(ap1, as_v2h(TQ[2 + rr_][c_]), acc_);                    \
            acc_ = fdot2_(ap2, as_v2h(TQ[4 + rr_][c_]), acc_);                    \
            acc_ = fdot2_(ap3, as_v2h(TQ[6 + rr_][c_]), acc_);                    \
            r_a[m_] = acc_;                                                       \
        }                                                                         \
        if (MAIN_LOW) { RED_LOW_ALL(r_a) } else { RED_HIGH_ALL(r_a) }             \
        r_a[0] *= E0.x; r_a[1] *= E0.y; r_a[2] *= E0.z; r_a[3] *= E0.w;           \
        r_a[4] *= E1.x; r_a[5] *= E1.y; r_a[6] *= E1.z; r_a[7] *= E1.w;           \
        float s_ = ((r_a[0] + r_a[1]) + (r_a[2] + r_a[3])) +                      \
                   ((r_a[4] + r_a[5]) + (r_a[6] + r_a[7]));                       \
        if (MAIN_LOW) {                                                           \
            s_ += __shfl_xor(s_, 8); s_ += __shfl_xor(s_, 16); s_ += __shfl_xor(s_, 32); \
        } else {                                                                  \
            s_ = dpp_add<0xB1>(s_); s_ = dpp_add<0x4E>(s_); s_ = dpp_add<0x141>(s_); \
        }                                                                         \
        int e_;                                                                   \
        (void)frexpf(s_, &e_);                                                    \
        eacc += e_;                                                               \
        const int me_ = -e_;                                                      \
        _Pragma("unroll")                                                         \
        for (int m_ = 0; m_ < 8; ++m_) ab[m_] = ldexpf(r_a[m_], me_);             \
    }

// ---------------- prep kernels ----------------
__global__ __launch_bounds__(256) void prep_emit(const float* __restrict__ log_emit) {
    int idx = blockIdx.x * 256 + threadIdx.x;  // 0..65535
    int v = idx >> 6;
    int j = idx & 63;
    gEmitT[idx] = expf(log_emit[(j + 1) * HMM_V + v]);
}

__global__ __launch_bounds__(64) void prep_small(const float* __restrict__ log_trans,
                                                 const float* __restrict__ log_pi) {
    int j = threadIdx.x;  // live state j+1
    for (int i = 0; i < 64; ++i)
        gET[i * 64 + j] = expf(log_trans[(i + 1) * HMM_S + (j + 1)]);
    float s = 0.f;
    for (int i = 0; i < HMM_S; ++i)
        s += expf(log_pi[i]) * expf(log_trans[i * HMM_S + (j + 1)]);
    gArow0[j] = s;
    float tc = log_trans[(j + 1) * HMM_S + 0];
    float mx = tc;
    for (int d = 1; d < 64; d <<= 1) mx = fmaxf(mx, __shfl_xor(mx, d));
    gTcs[j] = expf(tc - mx);
    if (j == 0) gTcmax = mx;
    for (int i = 0; i < 64; ++i)
        gP1[blk_idx(i, j)] = (__fp16)gET[i * 64 + j];
}

__global__ __launch_bounds__(64) void prep_table() {
    __shared__ float ETs[64 * 64];  // [i][j]
    __shared__ float ETp[64 * 66];  // [j][m], padded
    __shared__ float ev[64];
    const int m = threadIdx.x;
    const int v = blockIdx.x;
    for (int i = 0; i < 64; ++i) ETs[i * 64 + m] = gET[i * 64 + m];
    for (int j = 0; j < 64; ++j) ETp[j * 66 + m] = gET[j * 64 + m];
    ev[m] = gEmitT[v * 64 + m];
    __syncthreads();
    float acc[64];
#pragma unroll
    for (int i = 0; i < 64; ++i) acc[i] = 0.f;
    for (int j = 0; j < 64; ++j) {
        float w = ev[j] * ETp[j * 66 + m];
#pragma unroll
        for (int i = 0; i < 64; ++i) acc[i] = fmaf(ETs[i * 64 + j], w, acc[i]);
    }
    float mx = acc[0];
#pragma unroll
    for (int i = 1; i < 64; ++i) mx = fmaxf(mx, acc[i]);
    for (int d = 1; d < 64; d <<= 1) mx = fmaxf(mx, __shfl_xor(mx, d));
    int e;
    (void)frexpf(mx, &e);
    float sc = exp2f((float)(11 - e));
    if (m == 0) gSlog[v] = (float)(e - 11) * (float)LN2;
    __fp16* outp = gMtab + v * 4096;
    for (int i = 0; i < 64; ++i) outp[blk_idx(i, m)] = (__fp16)(acc[i] * sc);
}

// ---------------- main serial-scan kernel: 1 wave per batch ----------------
__global__ __launch_bounds__(64, 1) void hmm_fwd(const int* __restrict__ obvs,
                                                 float* __restrict__ out) {
    __shared__ __attribute__((aligned(16))) unsigned short obs_w16[HMM_T + 32];
    __shared__ float a0lds[64];
    const int b = blockIdx.x;
    const int lane = threadIdx.x;
    const int l = lane & 7, h = lane >> 3;

    // ---- stage obs as u16 + separable slog sum (off the serial chain) ----
    float slsum = 0.f;
    {
        const int4* og = (const int4*)(obvs + b * HMM_T);
        ushort4* ow = (ushort4*)obs_w16;
        for (int it = lane; it < HMM_T / 4; it += 64) {
            int4 o = og[it];
            ow[it] = make_ushort4((unsigned short)o.x, (unsigned short)o.y,
                                  (unsigned short)o.z, (unsigned short)o.w);
            float sx = gSlog[o.x];  // app a = 2*it   (skip a=0: P1 has slog 0)
            float sz = gSlog[o.z];  // app a = 2*it+1
            slsum += (it != 0 ? sx : 0.f) + sz;
        }
        if (lane < 8) ow[HMM_T / 4 + lane] = make_ushort4(0, 0, 0, 0);
    }

    // ---- init t=0 (exact: includes bookend state) ----
    int o0 = obvs[b * HMM_T];
    float a0 = gArow0[lane] * gEmitT[o0 * 64 + lane];
    a0lds[lane] = a0;
    __syncthreads();  // staging + a0 handoff complete; vmcnt ~drained here

    float ab[8];
#pragma unroll
    for (int k = 0; k < 8; ++k) ab[k] = a0lds[l * 8 + k];  // ab[k] = alpha[8l+k]

    const uint* obs_w32 = (const uint*)obs_w16;  // word a = (obs[2a], obs[2a+1])
    const int blkEb = (l * 8 + h) * 128;  // byte offset of lane's table block, even apps
    const int blkOb = (h * 8 + l) * 128;  // odd apps
    const int ebEb = h * 32;              // byte offset of lane's emission pair, even
    const int ebOb = l * 32;              // odd

    int eacc = 0;

    // depth-4 register ring
    v4i qa[8], qb[8], qc[8], qd[8];
    v4f ea0, ea1, eb0, eb1, ec0, ec1, ed0, ed1;

    // ---- prologue: issue apps 0..3 (40 outstanding) ----
    ISSUE_APP(qa, ea0, ea1, obs_w32[0] & 0xFFFF0000u, gP1, blkEb, ebEb)  // app0: P1, v1 forced 0
    ISSUE_APP(qb, eb0, eb1, obs_w32[1], gMtab, blkOb, ebOb)
    ISSUE_APP(qc, ec0, ec1, obs_w32[2], gMtab, blkEb, ebEb)
    ISSUE_APP(qd, ed0, ed1, obs_w32[3], gMtab, blkOb, ebOb)
    uint obp0 = obs_w32[4], obp1 = obs_w32[5], obp2 = obs_w32[6], obp3 = obs_w32[7];

    // ---- main loop: wait(30) -> compute oldest -> reissue its slot 4 ahead ----
    for (int g = 0; g < 1024; ++g) {
        const int base = 4 * g;
        WAIT_TIE(qa, ea0, ea1);
        COMPUTE_APP(qa, ea0, ea1, true)                           // app base   (even)
        ISSUE_APP(qa, ea0, ea1, obp0, gMtab, blkEb, ebEb)         // app base+4 (even)
        obp0 = obs_w32[base + 8];
        WAIT_TIE(qb, eb0, eb1);
        COMPUTE_APP(qb, eb0, eb1, false)                          // app base+1 (odd)
        ISSUE_APP(qb, eb0, eb1, obp1, gMtab, blkOb, ebOb)         // app base+5 (odd)
        obp1 = obs_w32[base + 9];
        WAIT_TIE(qc, ec0, ec1);
        COMPUTE_APP(qc, ec0, ec1, true)                           // app base+2 (even)
        ISSUE_APP(qc, ec0, ec1, obp2, gMtab, blkEb, ebEb)         // app base+6 (even)
        obp2 = obs_w32[base + 10];
        WAIT_TIE(qd, ed0, ed1);
        COMPUTE_APP(qd, ed0, ed1, false)                          // app base+3 (odd)
        ISSUE_APP(qd, ed0, ed1, obp3, gMtab, blkOb, ebOb)         // app base+7 (odd)
        obp3 = obs_w32[base + 11];
    }
    asm volatile("s_waitcnt vmcnt(0)" ::: "memory");  // drain trailing speculative issues

    // ---- termination (last app odd): ab[m] = alpha[8l+m] ----
    float t = 0.f;
#pragma unroll
    for (int m = 0; m < 8; ++m) t += ab[m] * gTcs[l * 8 + m];
    t = dpp_add<0xB1>(t);
    t = dpp_add<0x4E>(t);
    t = dpp_add<0x141>(t);  // sum over the 8 l-groups
#pragma unroll
    for (int d = 1; d < 64; d <<= 1) slsum += __shfl_xor(slsum, d);
    if (lane == 0)
        out[b] = (float)((double)slsum + (double)eacc * LN2 + (double)gTcmax +
                         (double)__logf(t));
}

// ---------------- launch ----------------
extern "C" void kernel_launch(void* const* d_in, const int* in_sizes, int n_in,
                              void* d_out, int out_size, void* d_ws, size_t ws_size,
                              hipStream_t stream) {
    const float* log_trans = (const float*)d_in[0];  // 65*65
    const float* log_emit  = (const float*)d_in[1];  // 65*1024
    const float* log_pi    = (const float*)d_in[2];  // 65
    const int*   obvs      = (const int*)d_in[3];    // 128*8192
    float* out = (float*)d_out;

    prep_emit<<<256, 256, 0, stream>>>(log_emit);
    prep_small<<<1, 64, 0, stream>>>(log_trans, log_pi);
    prep_table<<<1024, 64, 0, stream>>>();
    hmm_fwd<<<HMM_B, 64, 0, stream>>>(obvs, out);
}

// Round 6
// 1195.027 us; speedup vs baseline: 1.8224x; 1.1949x over previous
//
#include <hip/hip_runtime.h>
#include <hip/hip_bf16.h>
#include <stdint.h>

// HMM batched forward, B=128, T=8192, S=65 (state 0 = bookend dead after init), V=1024.
//
// R6: remove ALL LDS-pipe ops from the serial alpha chain.
// R5 post-mortem: every app had 3 dependent ds_bpermute (__shfl_xor 8/16/32) on the
// chain (~100 cyc each) -> 785 cyc/app. Replacements:
//  - xor8  = DPP row_ror:8 (VALU)
//  - xor16 = v_permlane16_swap_b32 pair-add (gfx950 VALU op)
//  - xor32 = v_permlane32_swap_b32 pair-add (gfx950 VALU op)
//  - frexp/ldexp renorm -> post-emission sum, v_rcp multiply; exact bookkeeping via
//    lsacc -= log2f(inv) in a double (log of the ACTUAL multiplier applied).
//  - table/emission addresses via readfirstlane -> SGPR base (scalar pipe is free).
// VMEM prefetch ring (asm global_load_dwordx4, depth 4, s_waitcnt vmcnt(30)) kept
// verbatim from R5 -- it works.

#define HMM_B 128
#define HMM_T 8192
#define HMM_S 65
#define HMM_V 1024
#define LN2 0.6931471805599453

typedef __fp16 v2h __attribute__((ext_vector_type(2)));
typedef int    v4i __attribute__((ext_vector_type(4)));
typedef float  v4f __attribute__((ext_vector_type(4)));
typedef unsigned int uint;

// ---------------- device-global tables ----------------
__device__ __attribute__((aligned(16))) __fp16 gMtab[HMM_V * 4096]; // blocked 2-step tables
__device__ __attribute__((aligned(16))) __fp16 gP1[4096];           // blocked 1-step table
__device__ __attribute__((aligned(16))) float  gEmitT[HMM_V * 64];  // exp emissions [v][j]
__device__ float gSlog[HMM_V];   // per-v table scale correction (nats)
__device__ float gET[64 * 64];   // exp transitions, live states [i][j]
__device__ __attribute__((aligned(16))) float gArow0[64];
__device__ __attribute__((aligned(16))) float gTcs[64];  // exp(tcol - tcmax)
__device__ float gTcmax;

// blocked f16 layout: entry (i,m) -> block (i>>3, m>>3) of 64 f16 (128 B contiguous),
// within-block pair-major for dot2: ((i&7)>>1)*16 + (m&7)*2 + (i&1)
__device__ __forceinline__ int blk_idx(int i, int m) {
    return (((i >> 3) * 8 + (m >> 3)) * 64) + (((i & 7) >> 1) * 16) + ((m & 7) * 2) + (i & 1);
}

// ---------------- helpers ----------------
__device__ __forceinline__ float fdot2_(v2h a, v2h b, float c) {
#if __has_builtin(__builtin_amdgcn_fdot2)
    return __builtin_amdgcn_fdot2(a, b, c, false);
#else
    return c + (float)a.x * (float)b.x + (float)a.y * (float)b.y;
#endif
}

template <int CTRL>
__device__ __forceinline__ float dpp_add(float x) {
    // 0xB1=quad_perm xor1, 0x4E=quad_perm xor2, 0x141=row_half_mirror (xor7 after
    // xor1+xor2 quads are uniform), 0x128=row_ror:8 (= xor8 within a 16-lane row)
    return x + __int_as_float(__builtin_amdgcn_update_dpp(
                   0, __float_as_int(x), CTRL, 0xF, 0xF, true));
}

// xor16 / xor32 butterfly-add stages via gfx950 VALU permlane swaps:
// with a=b=x, the swap leaves {x[i], x[i^K]} split across (a,b) -> a+b is the stage.
__device__ __forceinline__ float p16x_add(float x) {
    float a = x, b = x;
    asm("v_permlane16_swap_b32 %0, %1" : "+v"(a), "+v"(b));
    return a + b;
}
__device__ __forceinline__ float p32x_add(float x) {
    float a = x, b = x;
    asm("v_permlane32_swap_b32 %0, %1" : "+v"(a), "+v"(b));
    return a + b;
}

__device__ __forceinline__ float fast_rcp(float x) {
#if __has_builtin(__builtin_amdgcn_rcpf)
    return __builtin_amdgcn_rcpf(x);
#else
    return 1.0f / x;
#endif
}

__device__ __forceinline__ v2h as_v2h(int x) { return __builtin_bit_cast(v2h, x); }

// issue exactly 10 global_load_dwordx4 for one app (8 table quads + 2 emission),
// SGPR base + per-lane VGPR offset (addresses are wave-uniform per app).
#define ISSUE_APP(TQ, E0, E1, W, TBASE, VBLK, VEB)                                \
    {                                                                             \
        uint w_ = (W);                                                            \
        uint u_ = (uint)__builtin_amdgcn_readfirstlane((int)w_);                  \
        const __fp16* tb_ = (TBASE) + (size_t)(u_ & 0xFFFFu) * 4096u;             \
        const float* eb_ = gEmitT + (size_t)(u_ >> 16) * 64u;                     \
        asm volatile("global_load_dwordx4 %0, %10, %12\n\t"                       \
                     "global_load_dwordx4 %1, %10, %12 offset:16\n\t"             \
                     "global_load_dwordx4 %2, %10, %12 offset:32\n\t"             \
                     "global_load_dwordx4 %3, %10, %12 offset:48\n\t"             \
                     "global_load_dwordx4 %4, %10, %12 offset:64\n\t"             \
                     "global_load_dwordx4 %5, %10, %12 offset:80\n\t"             \
                     "global_load_dwordx4 %6, %10, %12 offset:96\n\t"             \
                     "global_load_dwordx4 %7, %10, %12 offset:112\n\t"            \
                     "global_load_dwordx4 %8, %11, %13\n\t"                       \
                     "global_load_dwordx4 %9, %11, %13 offset:16"                 \
                     : "=&v"(TQ[0]), "=&v"(TQ[1]), "=&v"(TQ[2]), "=&v"(TQ[3]),    \
                       "=&v"(TQ[4]), "=&v"(TQ[5]), "=&v"(TQ[6]), "=&v"(TQ[7]),    \
                       "=&v"(E0), "=&v"(E1)                                       \
                     : "v"(VBLK), "v"(VEB), "s"(tb_), "s"(eb_)                    \
                     : "memory");                                                 \
    }

// wait until only 30 VMEM outstanding (drains the oldest 10 = the app about to be
// computed), tying all destination regs so consumers stay below the wait.
#define WAIT_TIE(TQ, E0, E1)                                                      \
    asm volatile("s_waitcnt vmcnt(30)"                                            \
                 : "+v"(TQ[0]), "+v"(TQ[1]), "+v"(TQ[2]), "+v"(TQ[3]),            \
                   "+v"(TQ[4]), "+v"(TQ[5]), "+v"(TQ[6]), "+v"(TQ[7]),            \
                   "+v"(E0), "+v"(E1)                                             \
                 :: "memory")

#define RED_LOW_ALL(r)                      \
    _Pragma("unroll")                       \
    for (int m_ = 0; m_ < 8; ++m_) {        \
        r[m_] = dpp_add<0xB1>(r[m_]);       \
        r[m_] = dpp_add<0x4E>(r[m_]);       \
        r[m_] = dpp_add<0x141>(r[m_]);      \
    }

#define RED_HIGH_ALL(r)                     \
    _Pragma("unroll")                       \
    for (int m_ = 0; m_ < 8; ++m_) {        \
        r[m_] = dpp_add<0x128>(r[m_]);      \
        r[m_] = p16x_add(r[m_]);            \
        r[m_] = p32x_add(r[m_]);            \
    }

// one application; table pair (p, col m) lives at TQ[2p + (m>>2)] component (m&3)
#define COMPUTE_APP(TQ, E0, E1, MAIN_LOW)                                         \
    {                                                                             \
        v2h ap0 = __builtin_amdgcn_cvt_pkrtz(ab[0], ab[1]);                       \
        v2h ap1 = __builtin_amdgcn_cvt_pkrtz(ab[2], ab[3]);                       \
        v2h ap2 = __builtin_amdgcn_cvt_pkrtz(ab[4], ab[5]);                       \
        v2h ap3 = __builtin_amdgcn_cvt_pkrtz(ab[6], ab[7]);                       \
        float r_a[8];                                                             \
        _Pragma("unroll")                                                         \
        for (int m_ = 0; m_ < 8; ++m_) {                                          \
            const int c_ = m_ & 3, rr_ = m_ >> 2;                                 \
            float acc_ = fdot2_(ap0, as_v2h(TQ[0 + rr_][c_]), 0.0f);              \
            acc_ = fdot2_(ap1, as_v2h(TQ[2 + rr_][c_]), acc_);                    \
            acc_ = fdot2_(ap2, as_v2h(TQ[4 + rr_][c_]), acc_);                    \
            acc_ = fdot2_(ap3, as_v2h(TQ[6 + rr_][c_]), acc_);                    \
            r_a[m_] = acc_;                                                       \
        }                                                                         \
        if (MAIN_LOW) { RED_LOW_ALL(r_a) } else { RED_HIGH_ALL(r_a) }             \
        r_a[0] *= E0.x; r_a[1] *= E0.y; r_a[2] *= E0.z; r_a[3] *= E0.w;           \
        r_a[4] *= E1.x; r_a[5] *= E1.y; r_a[6] *= E1.z; r_a[7] *= E1.w;           \
        float s_ = ((r_a[0] + r_a[1]) + (r_a[2] + r_a[3])) +                      \
                   ((r_a[4] + r_a[5]) + (r_a[6] + r_a[7]));                       \
        if (MAIN_LOW) {                                                           \
            s_ = dpp_add<0x128>(s_); s_ = p16x_add(s_); s_ = p32x_add(s_);        \
        } else {                                                                  \
            s_ = dpp_add<0xB1>(s_); s_ = dpp_add<0x4E>(s_); s_ = dpp_add<0x141>(s_); \
        }                                                                         \
        float inv_ = fast_rcp(s_);                                                \
        lsacc -= (double)__log2f(inv_);                                           \
        _Pragma("unroll")                                                         \
        for (int m_ = 0; m_ < 8; ++m_) ab[m_] = r_a[m_] * inv_;                   \
    }

// ---------------- prep kernels ----------------
__global__ __launch_bounds__(256) void prep_emit(const float* __restrict__ log_emit) {
    int idx = blockIdx.x * 256 + threadIdx.x;  // 0..65535
    int v = idx >> 6;
    int j = idx & 63;
    gEmitT[idx] = expf(log_emit[(j + 1) * HMM_V + v]);
}

__global__ __launch_bounds__(64) void prep_small(const float* __restrict__ log_trans,
                                                 const float* __restrict__ log_pi) {
    int j = threadIdx.x;  // live state j+1
    for (int i = 0; i < 64; ++i)
        gET[i * 64 + j] = expf(log_trans[(i + 1) * HMM_S + (j + 1)]);
    float s = 0.f;
    for (int i = 0; i < HMM_S; ++i)
        s += expf(log_pi[i]) * expf(log_trans[i * HMM_S + (j + 1)]);
    gArow0[j] = s;
    float tc = log_trans[(j + 1) * HMM_S + 0];
    float mx = tc;
    for (int d = 1; d < 64; d <<= 1) mx = fmaxf(mx, __shfl_xor(mx, d));
    gTcs[j] = expf(tc - mx);
    if (j == 0) gTcmax = mx;
    for (int i = 0; i < 64; ++i)
        gP1[blk_idx(i, j)] = (__fp16)gET[i * 64 + j];
}

__global__ __launch_bounds__(64) void prep_table() {
    __shared__ float ETs[64 * 64];  // [i][j]
    __shared__ float ETp[64 * 66];  // [j][m], padded
    __shared__ float ev[64];
    const int m = threadIdx.x;
    const int v = blockIdx.x;
    for (int i = 0; i < 64; ++i) ETs[i * 64 + m] = gET[i * 64 + m];
    for (int j = 0; j < 64; ++j) ETp[j * 66 + m] = gET[j * 64 + m];
    ev[m] = gEmitT[v * 64 + m];
    __syncthreads();
    float acc[64];
#pragma unroll
    for (int i = 0; i < 64; ++i) acc[i] = 0.f;
    for (int j = 0; j < 64; ++j) {
        float w = ev[j] * ETp[j * 66 + m];
#pragma unroll
        for (int i = 0; i < 64; ++i) acc[i] = fmaf(ETs[i * 64 + j], w, acc[i]);
    }
    float mx = acc[0];
#pragma unroll
    for (int i = 1; i < 64; ++i) mx = fmaxf(mx, acc[i]);
    for (int d = 1; d < 64; d <<= 1) mx = fmaxf(mx, __shfl_xor(mx, d));
    int e;
    (void)frexpf(mx, &e);
    float sc = exp2f((float)(11 - e));
    if (m == 0) gSlog[v] = (float)(e - 11) * (float)LN2;
    __fp16* outp = gMtab + v * 4096;
    for (int i = 0; i < 64; ++i) outp[blk_idx(i, m)] = (__fp16)(acc[i] * sc);
}

// ---------------- main serial-scan kernel: 1 wave per batch ----------------
__global__ __launch_bounds__(64, 1) void hmm_fwd(const int* __restrict__ obvs,
                                                 float* __restrict__ out) {
    __shared__ __attribute__((aligned(16))) unsigned short obs_w16[HMM_T + 32];
    __shared__ float a0lds[64];
    const int b = blockIdx.x;
    const int lane = threadIdx.x;
    const int l = lane & 7, h = lane >> 3;

    // ---- stage obs as u16 + separable slog sum (off the serial chain) ----
    float slsum = 0.f;
    {
        const int4* og = (const int4*)(obvs + b * HMM_T);
        ushort4* ow = (ushort4*)obs_w16;
        for (int it = lane; it < HMM_T / 4; it += 64) {
            int4 o = og[it];
            ow[it] = make_ushort4((unsigned short)o.x, (unsigned short)o.y,
                                  (unsigned short)o.z, (unsigned short)o.w);
            float sx = gSlog[o.x];  // app a = 2*it   (skip a=0: P1 has slog 0)
            float sz = gSlog[o.z];  // app a = 2*it+1
            slsum += (it != 0 ? sx : 0.f) + sz;
        }
        if (lane < 8) ow[HMM_T / 4 + lane] = make_ushort4(0, 0, 0, 0);
    }

    // ---- init t=0 (exact: includes bookend state) ----
    int o0 = obvs[b * HMM_T];
    float a0 = gArow0[lane] * gEmitT[o0 * 64 + lane];
    a0lds[lane] = a0;
    __syncthreads();  // staging + a0 handoff complete; vmcnt ~drained here

    float ab[8];
#pragma unroll
    for (int k = 0; k < 8; ++k) ab[k] = a0lds[l * 8 + k];  // ab[k] = alpha[8l+k]

    const uint* obs_w32 = (const uint*)obs_w16;  // word a = (obs[2a], obs[2a+1])
    const int blkEb = (l * 8 + h) * 128;  // byte offset of lane's table block, even apps
    const int blkOb = (h * 8 + l) * 128;  // odd apps
    const int ebEb = h * 32;              // byte offset of lane's emission pair, even
    const int ebOb = l * 32;              // odd

    double lsacc = 0.0;  // sum of log2(applied normalization divisors)

    // depth-4 register ring
    v4i qa[8], qb[8], qc[8], qd[8];
    v4f ea0, ea1, eb0, eb1, ec0, ec1, ed0, ed1;

    // ---- prologue: issue apps 0..3 (40 outstanding) ----
    ISSUE_APP(qa, ea0, ea1, obs_w32[0] & 0xFFFF0000u, gP1, blkEb, ebEb)  // app0: P1, v1 forced 0
    ISSUE_APP(qb, eb0, eb1, obs_w32[1], gMtab, blkOb, ebOb)
    ISSUE_APP(qc, ec0, ec1, obs_w32[2], gMtab, blkEb, ebEb)
    ISSUE_APP(qd, ed0, ed1, obs_w32[3], gMtab, blkOb, ebOb)
    uint obp0 = obs_w32[4], obp1 = obs_w32[5], obp2 = obs_w32[6], obp3 = obs_w32[7];

    // ---- main loop: wait(30) -> compute oldest -> reissue its slot 4 ahead ----
    for (int g = 0; g < 1024; ++g) {
        const int base = 4 * g;
        WAIT_TIE(qa, ea0, ea1);
        COMPUTE_APP(qa, ea0, ea1, true)                           // app base   (even)
        ISSUE_APP(qa, ea0, ea1, obp0, gMtab, blkEb, ebEb)         // app base+4 (even)
        obp0 = obs_w32[base + 8];
        WAIT_TIE(qb, eb0, eb1);
        COMPUTE_APP(qb, eb0, eb1, false)                          // app base+1 (odd)
        ISSUE_APP(qb, eb0, eb1, obp1, gMtab, blkOb, ebOb)         // app base+5 (odd)
        obp1 = obs_w32[base + 9];
        WAIT_TIE(qc, ec0, ec1);
        COMPUTE_APP(qc, ec0, ec1, true)                           // app base+2 (even)
        ISSUE_APP(qc, ec0, ec1, obp2, gMtab, blkEb, ebEb)         // app base+6 (even)
        obp2 = obs_w32[base + 10];
        WAIT_TIE(qd, ed0, ed1);
        COMPUTE_APP(qd, ed0, ed1, false)                          // app base+3 (odd)
        ISSUE_APP(qd, ed0, ed1, obp3, gMtab, blkOb, ebOb)         // app base+7 (odd)
        obp3 = obs_w32[base + 11];
    }
    asm volatile("s_waitcnt vmcnt(0)" ::: "memory");  // drain trailing speculative issues

    // ---- termination (last app odd): ab[m] = alpha[8l+m], replicated across h ----
    float t = 0.f;
#pragma unroll
    for (int m = 0; m < 8; ++m) t += ab[m] * gTcs[l * 8 + m];
    t = dpp_add<0xB1>(t);
    t = dpp_add<0x4E>(t);
    t = dpp_add<0x141>(t);  // sum over the 8 l-groups
#pragma unroll
    for (int d = 1; d < 64; d <<= 1) slsum += __shfl_xor(slsum, d);
    if (lane == 0)
        out[b] = (float)((double)slsum + lsacc * LN2 + (double)gTcmax +
                         (double)__logf(t));
}

// ---------------- launch ----------------
extern "C" void kernel_launch(void* const* d_in, const int* in_sizes, int n_in,
                              void* d_out, int out_size, void* d_ws, size_t ws_size,
                              hipStream_t stream) {
    const float* log_trans = (const float*)d_in[0];  // 65*65
    const float* log_emit  = (const float*)d_in[1];  // 65*1024
    const float* log_pi    = (const float*)d_in[2];  // 65
    const int*   obvs      = (const int*)d_in[3];    // 128*8192
    float* out = (float*)d_out;

    prep_emit<<<256, 256, 0, stream>>>(log_emit);
    prep_small<<<1, 64, 0, stream>>>(log_trans, log_pi);
    prep_table<<<1024, 64, 0, stream>>>();
    hmm_fwd<<<HMM_B, 64, 0, stream>>>(obvs, out);
}

// Round 7
// 932.521 us; speedup vs baseline: 2.3353x; 1.2815x over previous
//
#include <hip/hip_runtime.h>
#include <hip/hip_bf16.h>
#include <stdint.h>

// HMM batched forward, B=128, T=8192, S=65 (state 0 = bookend dead after init), V=1024.
//
// R7: MFMA matvec. R6 post-mortem: kernel is issue-bound (78% of the 1-wave issue
// ceiling); dot2+butterfly costs ~250 instr/app. Replace with 8x
// v_mfma_f32_16x16x32_f16 using the replicated-A trick: A[m][k] = alpha_chunk[k]
// for all rows m -> D rows replicate; lane holds y[16u + (lane&15)] for col-tiles
// u=0..3. Table pre-swizzled into exact B-fragment layout (B[k][n]: n=lane&15,
// k=(lane>>4)*8+j), fetched via the proven R5/R6 asm prefetch ring (9 loads/app,
// depth 4, s_waitcnt vmcnt(27)). Renorm: within-16 DPP butterfly (4 stages, D is
// replicated across lane>>4) + v_rcp; exact bookkeeping lsacc -= log2f(inv).
// A-fragment rebuild: pack 4 f32 -> 2 f16x2 regs, 8 ds_bpermute with the fixed
// permutation srclane = 4*(lane>>4)+q; sigma_in baked into the table by prep.
// No parity asymmetry anymore -- all apps identical.

#define HMM_B 128
#define HMM_T 8192
#define HMM_S 65
#define HMM_V 1024
#define LN2 0.6931471805599453

typedef _Float16 h8 __attribute__((ext_vector_type(8)));
typedef int    v4i __attribute__((ext_vector_type(4)));
typedef float  v4f __attribute__((ext_vector_type(4)));
typedef unsigned int uint;

// ---------------- device-global tables ----------------
// gMtab[v]: 2-step fused matrix in B-frag layout, 8KB each.
//   f16 slot (r*64 + L)*8 + j  holds  M2[sigma_in(32*(r>>2) + 8*(L>>4) + j)][16*(r&3) + (L&15)]
//   where sigma_in(32t+8g+j) = 16*(2t + (j&1)) + 4g + (j>>1).
__device__ __attribute__((aligned(16))) __fp16 gMtab[HMM_V * 4096];
__device__ __attribute__((aligned(16))) __fp16 gP1[4096];            // app-0 1-step table (ET*1024), same layout
__device__ __attribute__((aligned(16))) float  gEmitT2[HMM_V * 64];  // [v][(c)*4 + u] = exp emission of live state 16u+c
__device__ float gSlog[HMM_V];   // per-v table scale correction (nats)
__device__ float gET[64 * 64];   // exp transitions, live states [i][j]
__device__ __attribute__((aligned(16))) float gArow0[64];
__device__ __attribute__((aligned(16))) float gTcs2[64];  // [(c)*4+u] = exp(tcol[16u+c] - tcmax)
__device__ float gTcmax;

// frag-position transform: value M[i][n] goes to (r, lane, slot j)
__device__ __forceinline__ void frag_pos(int i, int n, int* r, int* lane, int* j) {
    int t = i >> 5, up = (i >> 4) & 1, g = (i & 15) >> 2, q = i & 3;
    *r = t * 4 + (n >> 4);
    *lane = g * 16 + (n & 15);
    *j = 2 * q + up;
}

// ---------------- helpers ----------------
template <int CTRL>
__device__ __forceinline__ float dpp_add(float x) {
    // 0xB1=quad_perm xor1, 0x4E=quad_perm xor2, 0x141=row_half_mirror, 0x128=row_ror:8
    return x + __int_as_float(__builtin_amdgcn_update_dpp(
                   0, __float_as_int(x), CTRL, 0xF, 0xF, true));
}
// full reduce within 16 lanes (inputs already replicated across lane>>4 groups)
#define DPP16_SUM(S)            \
    S = dpp_add<0xB1>(S);       \
    S = dpp_add<0x4E>(S);       \
    S = dpp_add<0x141>(S);      \
    S = dpp_add<0x128>(S);

__device__ __forceinline__ float fast_rcp(float x) {
#if __has_builtin(__builtin_amdgcn_rcpf)
    return __builtin_amdgcn_rcpf(x);
#else
    return 1.0f / x;
#endif
}

__device__ __forceinline__ h8 bfrag(v4i q) { return __builtin_bit_cast(h8, q); }
__device__ __forceinline__ int pkh(float a, float b) {
    return __builtin_bit_cast(int, __builtin_amdgcn_cvt_pkrtz(a, b));
}

#define MFMA16(A, B, C) __builtin_amdgcn_mfma_f32_16x16x32_f16((A), (B), (C), 0, 0, 0)

// issue exactly 9 global_load_dwordx4 for one app (8 table quads + 1 emission).
// Table: lane L reads int4 (r*64+L), r=0..7 -> two SGPR bases (r<4, r>=4), imm r*1024.
#define ISSUE_APP(TQ, EV, W, TBASE)                                               \
    {                                                                             \
        uint w_ = (W);                                                            \
        uint u_ = (uint)__builtin_amdgcn_readfirstlane((int)w_);                  \
        const __fp16* t0_ = (TBASE) + (size_t)(u_ & 0xFFFFu) * 4096u;             \
        const __fp16* t1_ = t0_ + 2048;                                           \
        const float* eb_ = gEmitT2 + (size_t)(u_ >> 16) * 64u;                    \
        asm volatile("global_load_dwordx4 %0, %9, %11\n\t"                        \
                     "global_load_dwordx4 %1, %9, %11 offset:1024\n\t"            \
                     "global_load_dwordx4 %2, %9, %11 offset:2048\n\t"            \
                     "global_load_dwordx4 %3, %9, %11 offset:3072\n\t"            \
                     "global_load_dwordx4 %4, %9, %12\n\t"                        \
                     "global_load_dwordx4 %5, %9, %12 offset:1024\n\t"            \
                     "global_load_dwordx4 %6, %9, %12 offset:2048\n\t"            \
                     "global_load_dwordx4 %7, %9, %12 offset:3072\n\t"            \
                     "global_load_dwordx4 %8, %10, %13"                           \
                     : "=&v"(TQ[0]), "=&v"(TQ[1]), "=&v"(TQ[2]), "=&v"(TQ[3]),    \
                       "=&v"(TQ[4]), "=&v"(TQ[5]), "=&v"(TQ[6]), "=&v"(TQ[7]),    \
                       "=&v"(EV)                                                  \
                     : "v"(vofft), "v"(voffe), "s"(t0_), "s"(t1_), "s"(eb_)       \
                     : "memory");                                                 \
    }

// drain the oldest 9 loads (= the app about to be computed); tie dests below the wait
#define WAIT_TIE(TQ, EV)                                                          \
    asm volatile("s_waitcnt vmcnt(27)"                                            \
                 : "+v"(TQ[0]), "+v"(TQ[1]), "+v"(TQ[2]), "+v"(TQ[3]),            \
                   "+v"(TQ[4]), "+v"(TQ[5]), "+v"(TQ[6]), "+v"(TQ[7]),            \
                   "+v"(EV)                                                       \
                 :: "memory")

// one application: 8 MFMA -> emission -> renorm -> pack -> 8 bpermute -> new A frags
#define COMPUTE_APP(TQ, EV)                                                       \
    {                                                                             \
        v4f z4 = {0.f, 0.f, 0.f, 0.f};                                            \
        v4f d0 = MFMA16(af0, bfrag(TQ[0]), z4);                                   \
        v4f d1 = MFMA16(af0, bfrag(TQ[1]), z4);                                   \
        v4f d2 = MFMA16(af0, bfrag(TQ[2]), z4);                                   \
        v4f d3 = MFMA16(af0, bfrag(TQ[3]), z4);                                   \
        d0 = MFMA16(af1, bfrag(TQ[4]), d0);                                       \
        d1 = MFMA16(af1, bfrag(TQ[5]), d1);                                       \
        d2 = MFMA16(af1, bfrag(TQ[6]), d2);                                       \
        d3 = MFMA16(af1, bfrag(TQ[7]), d3);                                       \
        float w0 = d0[0] * EV.x, w1 = d1[0] * EV.y;                               \
        float w2 = d2[0] * EV.z, w3 = d3[0] * EV.w;                               \
        float s_ = (w0 + w1) + (w2 + w3);                                         \
        DPP16_SUM(s_)                                                             \
        float inv_ = fast_rcp(s_);                                                \
        lsacc -= (double)__log2f(inv_);                                           \
        zn0 = w0 * inv_; zn1 = w1 * inv_;                                         \
        zn2 = w2 * inv_; zn3 = w3 * inv_;                                         \
        int p0_ = pkh(zn0, zn1), p1_ = pkh(zn2, zn3);                             \
        v4i a0_, a1_;                                                             \
        a0_[0] = __builtin_amdgcn_ds_bpermute(idx0, p0_);                         \
        a0_[1] = __builtin_amdgcn_ds_bpermute(idx1, p0_);                         \
        a0_[2] = __builtin_amdgcn_ds_bpermute(idx2, p0_);                         \
        a0_[3] = __builtin_amdgcn_ds_bpermute(idx3, p0_);                         \
        a1_[0] = __builtin_amdgcn_ds_bpermute(idx0, p1_);                         \
        a1_[1] = __builtin_amdgcn_ds_bpermute(idx1, p1_);                         \
        a1_[2] = __builtin_amdgcn_ds_bpermute(idx2, p1_);                         \
        a1_[3] = __builtin_amdgcn_ds_bpermute(idx3, p1_);                         \
        af0 = bfrag(a0_); af1 = bfrag(a1_);                                       \
    }

// ---------------- prep kernels ----------------
__global__ __launch_bounds__(256) void prep_emit(const float* __restrict__ log_emit) {
    int idx = blockIdx.x * 256 + threadIdx.x;  // 0..65535
    int v = idx >> 6;
    int j = idx & 63;  // live state j (HMM state j+1)
    gEmitT2[v * 64 + (j & 15) * 4 + (j >> 4)] = expf(log_emit[(j + 1) * HMM_V + v]);
}

__global__ __launch_bounds__(64) void prep_small(const float* __restrict__ log_trans,
                                                 const float* __restrict__ log_pi) {
    int j = threadIdx.x;  // live state j (HMM state j+1)
    for (int i = 0; i < 64; ++i)
        gET[i * 64 + j] = expf(log_trans[(i + 1) * HMM_S + (j + 1)]);
    float s = 0.f;
    for (int i = 0; i < HMM_S; ++i)
        s += expf(log_pi[i]) * expf(log_trans[i * HMM_S + (j + 1)]);
    gArow0[j] = s;
    float tc = log_trans[(j + 1) * HMM_S + 0];
    float mx = tc;
    for (int d = 1; d < 64; d <<= 1) mx = fmaxf(mx, __shfl_xor(mx, d));
    gTcs2[(j & 15) * 4 + (j >> 4)] = expf(tc - mx);
    if (j == 0) gTcmax = mx;
    // app-0 1-step table in B-frag layout, scaled 2^10 (avoids f16 subnormals);
    // the constant scale is repaid once in hmm_fwd's lsacc init (-10).
    for (int i = 0; i < 64; ++i) {
        int r, lane, sj;
        frag_pos(i, j, &r, &lane, &sj);
        gP1[(r * 64 + lane) * 8 + sj] = (__fp16)(gET[i * 64 + j] * 1024.0f);
    }
}

__global__ __launch_bounds__(64) void prep_table() {
    __shared__ float ETs[64 * 64];  // [i][j]
    __shared__ float ETp[64 * 66];  // [j][m], padded
    __shared__ float ev[64];
    const int m = threadIdx.x;
    const int v = blockIdx.x;
    for (int i = 0; i < 64; ++i) ETs[i * 64 + m] = gET[i * 64 + m];
    for (int j = 0; j < 64; ++j) ETp[j * 66 + m] = gET[j * 64 + m];
    ev[m] = gEmitT2[v * 64 + (m & 15) * 4 + (m >> 4)];
    __syncthreads();
    float acc[64];
#pragma unroll
    for (int i = 0; i < 64; ++i) acc[i] = 0.f;
    for (int j = 0; j < 64; ++j) {
        float w = ev[j] * ETp[j * 66 + m];
#pragma unroll
        for (int i = 0; i < 64; ++i) acc[i] = fmaf(ETs[i * 64 + j], w, acc[i]);
    }
    float mx = acc[0];
#pragma unroll
    for (int i = 1; i < 64; ++i) mx = fmaxf(mx, acc[i]);
    for (int d = 1; d < 64; d <<= 1) mx = fmaxf(mx, __shfl_xor(mx, d));
    int e;
    (void)frexpf(mx, &e);
    float sc = exp2f((float)(11 - e));
    if (m == 0) gSlog[v] = (float)(e - 11) * (float)LN2;
    for (int i = 0; i < 64; ++i) {
        int r, lane, sj;
        frag_pos(i, m, &r, &lane, &sj);
        gMtab[v * 4096 + (r * 64 + lane) * 8 + sj] = (__fp16)(acc[i] * sc);
    }
}

// ---------------- main serial-scan kernel: 1 wave per batch ----------------
__global__ __launch_bounds__(64, 1) void hmm_fwd(const int* __restrict__ obvs,
                                                 float* __restrict__ out) {
    __shared__ __attribute__((aligned(16))) unsigned short obs_w16[HMM_T + 32];
    __shared__ float a0lds[64];
    const int b = blockIdx.x;
    const int lane = threadIdx.x;

    // ---- stage obs as u16 + separable slog sum (off the serial chain) ----
    float slsum = 0.f;
    {
        const int4* og = (const int4*)(obvs + b * HMM_T);
        ushort4* ow = (ushort4*)obs_w16;
        for (int it = lane; it < HMM_T / 4; it += 64) {
            int4 o = og[it];
            ow[it] = make_ushort4((unsigned short)o.x, (unsigned short)o.y,
                                  (unsigned short)o.z, (unsigned short)o.w);
            float sx = gSlog[o.x];  // app 2*it (skip it==0: app0 is P1)
            float sz = gSlog[o.z];  // app 2*it+1
            slsum += (it != 0 ? sx : 0.f) + sz;
        }
        if (lane < 8) ow[HMM_T / 4 + lane] = make_ushort4(0, 0, 0, 0);
    }

    // ---- init t=0 (exact: includes bookend state), normalize into f16 range ----
    int o0 = obvs[b * HMM_T];
    float a0 = gArow0[lane] * gEmitT2[o0 * 64 + (lane & 15) * 4 + (lane >> 4)];
    float s0 = a0;
#pragma unroll
    for (int d = 1; d < 64; d <<= 1) s0 += __shfl_xor(s0, d);
    a0lds[lane] = a0 / s0;
    __syncthreads();  // obs staging + a0 handoff

    double lsacc = (double)__log2f(s0) - 10.0;  // -10 repays gP1's 2^10 scale

    // A fragments: af_t slot (g=lane>>4, j) = alpha[sigma_in(32t+8g+j)]
    // sigma_in(32t+8g+j) = 16*(2t+(j&1)) + 4g + (j>>1)
    h8 af0, af1;
    {
        const int g4 = (lane >> 4) * 4;
        v4i a0_, a1_;
#pragma unroll
        for (int ri = 0; ri < 4; ++ri) {
            a0_[ri] = pkh(a0lds[g4 + ri], a0lds[16 + g4 + ri]);
            a1_[ri] = pkh(a0lds[32 + g4 + ri], a0lds[48 + g4 + ri]);
        }
        af0 = bfrag(a0_);
        af1 = bfrag(a1_);
    }
    float zn0 = 0.f, zn1 = 0.f, zn2 = 0.f, zn3 = 0.f;

    const uint* obs_w32 = (const uint*)obs_w16;   // word a = (obs[2a], obs[2a+1])
    const int vofft = lane * 16;                  // table int4 (r*64+L) -> L*16 + r*1024
    const int voffe = (lane & 15) * 16;           // emission float4 at c*16
    const int idx0 = (lane >> 4) * 16;            // bpermute byte idx: srclane 4g+q
    const int idx1 = idx0 + 4, idx2 = idx0 + 8, idx3 = idx0 + 12;

    // depth-4 register ring
    v4i qa[8], qb[8], qc[8], qd[8];
    v4f ea, eb, ec, ed;

    // ---- prologue: issue apps 0..3 (36 outstanding) ----
    ISSUE_APP(qa, ea, obs_w32[0] & 0xFFFF0000u, gP1)  // app0: P1, v1 forced 0
    ISSUE_APP(qb, eb, obs_w32[1], gMtab)
    ISSUE_APP(qc, ec, obs_w32[2], gMtab)
    ISSUE_APP(qd, ed, obs_w32[3], gMtab)
    uint obp0 = obs_w32[4], obp1 = obs_w32[5], obp2 = obs_w32[6], obp3 = obs_w32[7];

    // ---- main loop: wait(27) -> compute oldest -> reissue its slot 4 ahead ----
    for (int g = 0; g < 1024; ++g) {
        const int base = 4 * g;
        WAIT_TIE(qa, ea);
        COMPUTE_APP(qa, ea)
        ISSUE_APP(qa, ea, obp0, gMtab)
        obp0 = obs_w32[base + 8];
        WAIT_TIE(qb, eb);
        COMPUTE_APP(qb, eb)
        ISSUE_APP(qb, eb, obp1, gMtab)
        obp1 = obs_w32[base + 9];
        WAIT_TIE(qc, ec);
        COMPUTE_APP(qc, ec)
        ISSUE_APP(qc, ec, obp2, gMtab)
        obp2 = obs_w32[base + 10];
        WAIT_TIE(qd, ed);
        COMPUTE_APP(qd, ed)
        ISSUE_APP(qd, ed, obp3, gMtab)
        obp3 = obs_w32[base + 11];
    }
    asm volatile("s_waitcnt vmcnt(0)" ::: "memory");  // drain trailing speculative issues

    // ---- termination: zn_u = alpha_final[16u + c], replicated across lane>>4 ----
    const float4 tc4 = *(const float4*)(gTcs2 + (lane & 15) * 4);
    float t = zn0 * tc4.x + zn1 * tc4.y + zn2 * tc4.z + zn3 * tc4.w;
    DPP16_SUM(t)
#pragma unroll
    for (int d = 1; d < 64; d <<= 1) slsum += __shfl_xor(slsum, d);
    if (lane == 0)
        out[b] = (float)((double)slsum + lsacc * LN2 + (double)gTcmax +
                         (double)__logf(t));
}

// ---------------- launch ----------------
extern "C" void kernel_launch(void* const* d_in, const int* in_sizes, int n_in,
                              void* d_out, int out_size, void* d_ws, size_t ws_size,
                              hipStream_t stream) {
    const float* log_trans = (const float*)d_in[0];  // 65*65
    const float* log_emit  = (const float*)d_in[1];  // 65*1024
    const float* log_pi    = (const float*)d_in[2];  // 65
    const int*   obvs      = (const int*)d_in[3];    // 128*8192
    float* out = (float*)d_out;

    prep_emit<<<256, 256, 0, stream>>>(log_emit);
    prep_small<<<1, 64, 0, stream>>>(log_trans, log_pi);
    prep_table<<<1024, 64, 0, stream>>>();
    hmm_fwd<<<HMM_B, 64, 0, stream>>>(obvs, out);
}

// Round 8
// 826.500 us; speedup vs baseline: 2.6349x; 1.1283x over previous
//
#include <hip/hip_runtime.h>
#include <hip/hip_bf16.h>
#include <stdint.h>

// HMM batched forward, B=128, T=8192, S=65 (state 0 = bookend dead after init), V=1024.
//
// R8: chain surgery on the R7 MFMA kernel (495 cyc/app, latency-bound).
//  (1) K-halves in parallel: af0/af1 MFMAs into independent accumulators,
//      combined by one scalar add per tile (rows replicated -> only reg 0 used).
//      Removes the dependent-MFMA C-chain (~55 cyc).
//  (2) One-app-stale normalization: app t scales by inv(s_{t-1}); the
//      sum->DPP16->rcp subchain (~45 cyc) moves off the alpha chain. Exact
//      bookkeeping: lsacc -= log2(inv actually applied); last app's inv is
//      computed but never applied (correctly excluded). Packed values bounded
//      by table max 2^11 << f16 max 2^16 -> no overflow.
// Everything else (asm prefetch ring depth 4, vmcnt(27), B-frag table,
// replicated-A MFMA, 8 ds_bpermute rebuild) unchanged from R7.

#define HMM_B 128
#define HMM_T 8192
#define HMM_S 65
#define HMM_V 1024
#define LN2 0.6931471805599453

typedef _Float16 h8 __attribute__((ext_vector_type(8)));
typedef int    v4i __attribute__((ext_vector_type(4)));
typedef float  v4f __attribute__((ext_vector_type(4)));
typedef unsigned int uint;

// ---------------- device-global tables ----------------
// gMtab[v]: 2-step fused matrix in B-frag layout, 8KB each.
//   f16 slot (r*64 + L)*8 + j  holds  M2[sigma_in(32*(r>>2) + 8*(L>>4) + j)][16*(r&3) + (L&15)]
//   where sigma_in(32t+8g+j) = 16*(2t + (j&1)) + 4g + (j>>1).
__device__ __attribute__((aligned(16))) __fp16 gMtab[HMM_V * 4096];
__device__ __attribute__((aligned(16))) __fp16 gP1[4096];            // app-0 1-step table (ET*1024), same layout
__device__ __attribute__((aligned(16))) float  gEmitT2[HMM_V * 64];  // [v][(c)*4 + u] = exp emission of live state 16u+c
__device__ float gSlog[HMM_V];   // per-v table scale correction (nats)
__device__ float gET[64 * 64];   // exp transitions, live states [i][j]
__device__ __attribute__((aligned(16))) float gArow0[64];
__device__ __attribute__((aligned(16))) float gTcs2[64];  // [(c)*4+u] = exp(tcol[16u+c] - tcmax)
__device__ float gTcmax;

// frag-position transform: value M[i][n] goes to (r, lane, slot j)
__device__ __forceinline__ void frag_pos(int i, int n, int* r, int* lane, int* j) {
    int t = i >> 5, up = (i >> 4) & 1, g = (i & 15) >> 2, q = i & 3;
    *r = t * 4 + (n >> 4);
    *lane = g * 16 + (n & 15);
    *j = 2 * q + up;
}

// ---------------- helpers ----------------
template <int CTRL>
__device__ __forceinline__ float dpp_add(float x) {
    // 0xB1=quad_perm xor1, 0x4E=quad_perm xor2, 0x141=row_half_mirror, 0x128=row_ror:8
    return x + __int_as_float(__builtin_amdgcn_update_dpp(
                   0, __float_as_int(x), CTRL, 0xF, 0xF, true));
}
// full reduce within 16 lanes (inputs already replicated across lane>>4 groups)
#define DPP16_SUM(S)            \
    S = dpp_add<0xB1>(S);       \
    S = dpp_add<0x4E>(S);       \
    S = dpp_add<0x141>(S);      \
    S = dpp_add<0x128>(S);

__device__ __forceinline__ float fast_rcp(float x) {
#if __has_builtin(__builtin_amdgcn_rcpf)
    return __builtin_amdgcn_rcpf(x);
#else
    return 1.0f / x;
#endif
}

__device__ __forceinline__ h8 bfrag(v4i q) { return __builtin_bit_cast(h8, q); }
__device__ __forceinline__ int pkh(float a, float b) {
    return __builtin_bit_cast(int, __builtin_amdgcn_cvt_pkrtz(a, b));
}

#define MFMA16(A, B, C) __builtin_amdgcn_mfma_f32_16x16x32_f16((A), (B), (C), 0, 0, 0)

// issue exactly 9 global_load_dwordx4 for one app (8 table quads + 1 emission).
// Table: lane L reads int4 (r*64+L), r=0..7 -> two SGPR bases (r<4, r>=4), imm r*1024.
#define ISSUE_APP(TQ, EV, W, TBASE)                                               \
    {                                                                             \
        uint w_ = (W);                                                            \
        uint u_ = (uint)__builtin_amdgcn_readfirstlane((int)w_);                  \
        const __fp16* t0_ = (TBASE) + (size_t)(u_ & 0xFFFFu) * 4096u;             \
        const __fp16* t1_ = t0_ + 2048;                                           \
        const float* eb_ = gEmitT2 + (size_t)(u_ >> 16) * 64u;                    \
        asm volatile("global_load_dwordx4 %0, %9, %11\n\t"                        \
                     "global_load_dwordx4 %1, %9, %11 offset:1024\n\t"            \
                     "global_load_dwordx4 %2, %9, %11 offset:2048\n\t"            \
                     "global_load_dwordx4 %3, %9, %11 offset:3072\n\t"            \
                     "global_load_dwordx4 %4, %9, %12\n\t"                        \
                     "global_load_dwordx4 %5, %9, %12 offset:1024\n\t"            \
                     "global_load_dwordx4 %6, %9, %12 offset:2048\n\t"            \
                     "global_load_dwordx4 %7, %9, %12 offset:3072\n\t"            \
                     "global_load_dwordx4 %8, %10, %13"                           \
                     : "=&v"(TQ[0]), "=&v"(TQ[1]), "=&v"(TQ[2]), "=&v"(TQ[3]),    \
                       "=&v"(TQ[4]), "=&v"(TQ[5]), "=&v"(TQ[6]), "=&v"(TQ[7]),    \
                       "=&v"(EV)                                                  \
                     : "v"(vofft), "v"(voffe), "s"(t0_), "s"(t1_), "s"(eb_)       \
                     : "memory");                                                 \
    }

// drain the oldest 9 loads (= the app about to be computed); tie dests below the wait
#define WAIT_TIE(TQ, EV)                                                          \
    asm volatile("s_waitcnt vmcnt(27)"                                            \
                 : "+v"(TQ[0]), "+v"(TQ[1]), "+v"(TQ[2]), "+v"(TQ[3]),            \
                   "+v"(TQ[4]), "+v"(TQ[5]), "+v"(TQ[6]), "+v"(TQ[7]),            \
                   "+v"(EV)                                                       \
                 :: "memory")

// one application: 8 independent MFMA -> tile-adds -> stale-inv scale -> pack ->
// 8 bpermute -> new A frags. Off-chain: this app's sum -> inv for the NEXT app.
#define COMPUTE_APP(TQ, EV)                                                       \
    {                                                                             \
        v4f z4 = {0.f, 0.f, 0.f, 0.f};                                            \
        v4f d0 = MFMA16(af0, bfrag(TQ[0]), z4);                                   \
        v4f d1 = MFMA16(af0, bfrag(TQ[1]), z4);                                   \
        v4f d2 = MFMA16(af0, bfrag(TQ[2]), z4);                                   \
        v4f d3 = MFMA16(af0, bfrag(TQ[3]), z4);                                   \
        v4f f0 = MFMA16(af1, bfrag(TQ[4]), z4);                                   \
        v4f f1 = MFMA16(af1, bfrag(TQ[5]), z4);                                   \
        v4f f2 = MFMA16(af1, bfrag(TQ[6]), z4);                                   \
        v4f f3 = MFMA16(af1, bfrag(TQ[7]), z4);                                   \
        float ei_ = inv;                                                          \
        float y0 = d0[0] + f0[0], y1 = d1[0] + f1[0];                             \
        float y2 = d2[0] + f2[0], y3 = d3[0] + f3[0];                             \
        zn0 = y0 * EV.x * ei_; zn1 = y1 * EV.y * ei_;                             \
        zn2 = y2 * EV.z * ei_; zn3 = y3 * EV.w * ei_;                             \
        int p0_ = pkh(zn0, zn1), p1_ = pkh(zn2, zn3);                             \
        v4i a0_, a1_;                                                             \
        a0_[0] = __builtin_amdgcn_ds_bpermute(idx0, p0_);                         \
        a0_[1] = __builtin_amdgcn_ds_bpermute(idx1, p0_);                         \
        a0_[2] = __builtin_amdgcn_ds_bpermute(idx2, p0_);                         \
        a0_[3] = __builtin_amdgcn_ds_bpermute(idx3, p0_);                         \
        a1_[0] = __builtin_amdgcn_ds_bpermute(idx0, p1_);                         \
        a1_[1] = __builtin_amdgcn_ds_bpermute(idx1, p1_);                         \
        a1_[2] = __builtin_amdgcn_ds_bpermute(idx2, p1_);                         \
        a1_[3] = __builtin_amdgcn_ds_bpermute(idx3, p1_);                         \
        af0 = bfrag(a0_); af1 = bfrag(a1_);                                       \
        /* off the alpha chain: bookkeeping + next app's inv */                   \
        lsacc -= (double)__log2f(ei_);                                            \
        float s_ = (zn0 + zn1) + (zn2 + zn3);                                     \
        DPP16_SUM(s_)                                                             \
        inv = fast_rcp(s_);                                                       \
    }

// ---------------- prep kernels ----------------
__global__ __launch_bounds__(256) void prep_emit(const float* __restrict__ log_emit) {
    int idx = blockIdx.x * 256 + threadIdx.x;  // 0..65535
    int v = idx >> 6;
    int j = idx & 63;  // live state j (HMM state j+1)
    gEmitT2[v * 64 + (j & 15) * 4 + (j >> 4)] = expf(log_emit[(j + 1) * HMM_V + v]);
}

__global__ __launch_bounds__(64) void prep_small(const float* __restrict__ log_trans,
                                                 const float* __restrict__ log_pi) {
    int j = threadIdx.x;  // live state j (HMM state j+1)
    for (int i = 0; i < 64; ++i)
        gET[i * 64 + j] = expf(log_trans[(i + 1) * HMM_S + (j + 1)]);
    float s = 0.f;
    for (int i = 0; i < HMM_S; ++i)
        s += expf(log_pi[i]) * expf(log_trans[i * HMM_S + (j + 1)]);
    gArow0[j] = s;
    float tc = log_trans[(j + 1) * HMM_S + 0];
    float mx = tc;
    for (int d = 1; d < 64; d <<= 1) mx = fmaxf(mx, __shfl_xor(mx, d));
    gTcs2[(j & 15) * 4 + (j >> 4)] = expf(tc - mx);
    if (j == 0) gTcmax = mx;
    // app-0 1-step table in B-frag layout, scaled 2^10 (avoids f16 subnormals);
    // the constant scale is repaid once in hmm_fwd's lsacc init (-10).
    for (int i = 0; i < 64; ++i) {
        int r, lane, sj;
        frag_pos(i, j, &r, &lane, &sj);
        gP1[(r * 64 + lane) * 8 + sj] = (__fp16)(gET[i * 64 + j] * 1024.0f);
    }
}

__global__ __launch_bounds__(64) void prep_table() {
    __shared__ float ETs[64 * 64];  // [i][j]
    __shared__ float ETp[64 * 66];  // [j][m], padded
    __shared__ float ev[64];
    const int m = threadIdx.x;
    const int v = blockIdx.x;
    for (int i = 0; i < 64; ++i) ETs[i * 64 + m] = gET[i * 64 + m];
    for (int j = 0; j < 64; ++j) ETp[j * 66 + m] = gET[j * 64 + m];
    ev[m] = gEmitT2[v * 64 + (m & 15) * 4 + (m >> 4)];
    __syncthreads();
    float acc[64];
#pragma unroll
    for (int i = 0; i < 64; ++i) acc[i] = 0.f;
    for (int j = 0; j < 64; ++j) {
        float w = ev[j] * ETp[j * 66 + m];
#pragma unroll
        for (int i = 0; i < 64; ++i) acc[i] = fmaf(ETs[i * 64 + j], w, acc[i]);
    }
    float mx = acc[0];
#pragma unroll
    for (int i = 1; i < 64; ++i) mx = fmaxf(mx, acc[i]);
    for (int d = 1; d < 64; d <<= 1) mx = fmaxf(mx, __shfl_xor(mx, d));
    int e;
    (void)frexpf(mx, &e);
    float sc = exp2f((float)(11 - e));
    if (m == 0) gSlog[v] = (float)(e - 11) * (float)LN2;
    for (int i = 0; i < 64; ++i) {
        int r, lane, sj;
        frag_pos(i, m, &r, &lane, &sj);
        gMtab[v * 4096 + (r * 64 + lane) * 8 + sj] = (__fp16)(acc[i] * sc);
    }
}

// ---------------- main serial-scan kernel: 1 wave per batch ----------------
__global__ __launch_bounds__(64, 1) void hmm_fwd(const int* __restrict__ obvs,
                                                 float* __restrict__ out) {
    __shared__ __attribute__((aligned(16))) unsigned short obs_w16[HMM_T + 32];
    __shared__ float a0lds[64];
    const int b = blockIdx.x;
    const int lane = threadIdx.x;

    // ---- stage obs as u16 + separable slog sum (off the serial chain) ----
    float slsum = 0.f;
    {
        const int4* og = (const int4*)(obvs + b * HMM_T);
        ushort4* ow = (ushort4*)obs_w16;
        for (int it = lane; it < HMM_T / 4; it += 64) {
            int4 o = og[it];
            ow[it] = make_ushort4((unsigned short)o.x, (unsigned short)o.y,
                                  (unsigned short)o.z, (unsigned short)o.w);
            float sx = gSlog[o.x];  // app 2*it (skip it==0: app0 is P1)
            float sz = gSlog[o.z];  // app 2*it+1
            slsum += (it != 0 ? sx : 0.f) + sz;
        }
        if (lane < 8) ow[HMM_T / 4 + lane] = make_ushort4(0, 0, 0, 0);
    }

    // ---- init t=0 (exact: includes bookend state), normalize into f16 range ----
    int o0 = obvs[b * HMM_T];
    float a0 = gArow0[lane] * gEmitT2[o0 * 64 + (lane & 15) * 4 + (lane >> 4)];
    float s0 = a0;
#pragma unroll
    for (int d = 1; d < 64; d <<= 1) s0 += __shfl_xor(s0, d);
    a0lds[lane] = a0 / s0;
    __syncthreads();  // obs staging + a0 handoff

    double lsacc = (double)__log2f(s0) - 10.0;  // -10 repays gP1's 2^10 scale

    // A fragments: af_t slot (g=lane>>4, j) = alpha[sigma_in(32t+8g+j)]
    // sigma_in(32t+8g+j) = 16*(2t+(j&1)) + 4g + (j>>1)
    h8 af0, af1;
    {
        const int g4 = (lane >> 4) * 4;
        v4i a0_, a1_;
#pragma unroll
        for (int ri = 0; ri < 4; ++ri) {
            a0_[ri] = pkh(a0lds[g4 + ri], a0lds[16 + g4 + ri]);
            a1_[ri] = pkh(a0lds[32 + g4 + ri], a0lds[48 + g4 + ri]);
        }
        af0 = bfrag(a0_);
        af1 = bfrag(a1_);
    }
    float zn0 = 0.f, zn1 = 0.f, zn2 = 0.f, zn3 = 0.f;
    float inv = 1.0f;  // stale normalizer: app t uses s_{t-1}; app 0 uses 1

    const uint* obs_w32 = (const uint*)obs_w16;   // word a = (obs[2a], obs[2a+1])
    const int vofft = lane * 16;                  // table int4 (r*64+L) -> L*16 + r*1024
    const int voffe = (lane & 15) * 16;           // emission float4 at c*16
    const int idx0 = (lane >> 4) * 16;            // bpermute byte idx: srclane 4g+q
    const int idx1 = idx0 + 4, idx2 = idx0 + 8, idx3 = idx0 + 12;

    // depth-4 register ring
    v4i qa[8], qb[8], qc[8], qd[8];
    v4f ea, eb, ec, ed;

    // ---- prologue: issue apps 0..3 (36 outstanding) ----
    ISSUE_APP(qa, ea, obs_w32[0] & 0xFFFF0000u, gP1)  // app0: P1, v1 forced 0
    ISSUE_APP(qb, eb, obs_w32[1], gMtab)
    ISSUE_APP(qc, ec, obs_w32[2], gMtab)
    ISSUE_APP(qd, ed, obs_w32[3], gMtab)
    uint obp0 = obs_w32[4], obp1 = obs_w32[5], obp2 = obs_w32[6], obp3 = obs_w32[7];

    // ---- main loop: wait(27) -> compute oldest -> reissue its slot 4 ahead ----
    for (int g = 0; g < 1024; ++g) {
        const int base = 4 * g;
        WAIT_TIE(qa, ea);
        COMPUTE_APP(qa, ea)
        ISSUE_APP(qa, ea, obp0, gMtab)
        obp0 = obs_w32[base + 8];
        WAIT_TIE(qb, eb);
        COMPUTE_APP(qb, eb)
        ISSUE_APP(qb, eb, obp1, gMtab)
        obp1 = obs_w32[base + 9];
        WAIT_TIE(qc, ec);
        COMPUTE_APP(qc, ec)
        ISSUE_APP(qc, ec, obp2, gMtab)
        obp2 = obs_w32[base + 10];
        WAIT_TIE(qd, ed);
        COMPUTE_APP(qd, ed)
        ISSUE_APP(qd, ed, obp3, gMtab)
        obp3 = obs_w32[base + 11];
    }
    asm volatile("s_waitcnt vmcnt(0)" ::: "memory");  // drain trailing speculative issues

    // ---- termination: zn_u = final ŵ[16u + c] (stale-normalized; lsacc has
    //      exactly the log of all applied divisors) ----
    const float4 tc4 = *(const float4*)(gTcs2 + (lane & 15) * 4);
    float t = zn0 * tc4.x + zn1 * tc4.y + zn2 * tc4.z + zn3 * tc4.w;
    DPP16_SUM(t)
#pragma unroll
    for (int d = 1; d < 64; d <<= 1) slsum += __shfl_xor(slsum, d);
    if (lane == 0)
        out[b] = (float)((double)slsum + lsacc * LN2 + (double)gTcmax +
                         (double)__logf(t));
}

// ---------------- launch ----------------
extern "C" void kernel_launch(void* const* d_in, const int* in_sizes, int n_in,
                              void* d_out, int out_size, void* d_ws, size_t ws_size,
                              hipStream_t stream) {
    const float* log_trans = (const float*)d_in[0];  // 65*65
    const float* log_emit  = (const float*)d_in[1];  // 65*1024
    const float* log_pi    = (const float*)d_in[2];  // 65
    const int*   obvs      = (const int*)d_in[3];    // 128*8192
    float* out = (float*)d_out;

    prep_emit<<<256, 256, 0, stream>>>(log_emit);
    prep_small<<<1, 64, 0, stream>>>(log_trans, log_pi);
    prep_table<<<1024, 64, 0, stream>>>();
    hmm_fwd<<<HMM_B, 64, 0, stream>>>(obvs, out);
}

// Round 10
// 541.703 us; speedup vs baseline: 4.0202x; 1.5257x over previous
//
#include <hip/hip_runtime.h>
#include <hip/hip_bf16.h>
#include <stdint.h>

// HMM batched forward, B=128, T=8192, S=65 (state 0 = bookend dead after init), V=1024.
//
// R10 = R9 with the prep_table staging-copy bug fixed: the frag image is 4096 f16
// = 512 int4, but the coalesced copy loops wrote only k<256 -> the r=4..7 half of
// every gMtab/gMtabT matrix stayed zero, silently dropping half the input states
// per app (~0.75 nats/app bias = the 3072-nat absmax). Loops now k<512.
//
// Design (R9): bidirectional split. L = tau^T (M_4095..M_2048)(M_2047..M_0) alpha0
// = g . f with f = fwd chain (apps 0..2047) and g = bwd chain applying
// O_a x = M_a (E_a o x) for a = 4095..2048 (table gMtabT = M^T in B-frag layout;
// emission multiply BEFORE the matvec). Two independent serial chains of 2048 apps
// as 256 blocks (128 batches x 2 dirs) = all 256 CUs. Per-app machinery = R8:
// asm global_load_dwordx4 depth-4 ring, s_waitcnt vmcnt(27), replicated-A MFMA
// (independent K-halves), stale-inv renorm, ds_bpermute A-rebuild.

#define HMM_B 128
#define HMM_T 8192
#define HMM_S 65
#define HMM_V 1024
#define LN2 0.6931471805599453

typedef _Float16 h8 __attribute__((ext_vector_type(8)));
typedef int    v4i __attribute__((ext_vector_type(4)));
typedef float  v4f __attribute__((ext_vector_type(4)));
typedef unsigned int uint;

// ---------------- device-global tables ----------------
__device__ __attribute__((aligned(16))) __fp16 gMtab[HMM_V * 4096];   // fused 2-step, B-frag
__device__ __attribute__((aligned(16))) __fp16 gMtabT[HMM_V * 4096];  // transposed, B-frag
__device__ __attribute__((aligned(16))) __fp16 gP1[4096];             // app-0 1-step (ET*2^10)
__device__ __attribute__((aligned(16))) float  gEmitT2[HMM_V * 64];   // [v][c*4+u] = e_v[16u+c]
__device__ float gSlog[HMM_V];
__device__ float gET[64 * 64];
__device__ __attribute__((aligned(16))) float gArow0[64];
__device__ __attribute__((aligned(16))) float gTcs2[64];  // [c*4+u] = exp(tcol[16u+c]-tcmax)
__device__ float gTcmax;
// split-scan handoff
__device__ __attribute__((aligned(16))) float gF[HMM_B * 64];
__device__ __attribute__((aligned(16))) float gG[HMM_B * 64];
__device__ double gLF[HMM_B];
__device__ double gLB[HMM_B];

// frag-position: value X[i][n] (input row i, output col n) -> (r, lane, slot j)
__device__ __forceinline__ void frag_pos(int i, int n, int* r, int* lane, int* j) {
    int t = i >> 5, up = (i >> 4) & 1, g = (i & 15) >> 2, q = i & 3;
    *r = t * 4 + (n >> 4);
    *lane = g * 16 + (n & 15);
    *j = 2 * q + up;
}

// ---------------- helpers ----------------
template <int CTRL>
__device__ __forceinline__ float dpp_add(float x) {
    return x + __int_as_float(__builtin_amdgcn_update_dpp(
                   0, __float_as_int(x), CTRL, 0xF, 0xF, true));
}
#define DPP16_SUM(S)            \
    S = dpp_add<0xB1>(S);       \
    S = dpp_add<0x4E>(S);       \
    S = dpp_add<0x141>(S);      \
    S = dpp_add<0x128>(S);

__device__ __forceinline__ float fast_rcp(float x) {
#if __has_builtin(__builtin_amdgcn_rcpf)
    return __builtin_amdgcn_rcpf(x);
#else
    return 1.0f / x;
#endif
}

__device__ __forceinline__ h8 bfrag(v4i q) { return __builtin_bit_cast(h8, q); }
__device__ __forceinline__ int pkh(float a, float b) {
    return __builtin_bit_cast(int, __builtin_amdgcn_cvt_pkrtz(a, b));
}

#define MFMA16(A, B, C) __builtin_amdgcn_mfma_f32_16x16x32_f16((A), (B), (C), 0, 0, 0)

#define ISSUE_APP(TQ, EV, W, TBASE)                                               \
    {                                                                             \
        uint w_ = (W);                                                            \
        uint u_ = (uint)__builtin_amdgcn_readfirstlane((int)w_);                  \
        const __fp16* t0_ = (TBASE) + (size_t)(u_ & 0xFFFFu) * 4096u;             \
        const __fp16* t1_ = t0_ + 2048;                                           \
        const float* eb_ = gEmitT2 + (size_t)(u_ >> 16) * 64u;                    \
        asm volatile("global_load_dwordx4 %0, %9, %11\n\t"                        \
                     "global_load_dwordx4 %1, %9, %11 offset:1024\n\t"            \
                     "global_load_dwordx4 %2, %9, %11 offset:2048\n\t"            \
                     "global_load_dwordx4 %3, %9, %11 offset:3072\n\t"            \
                     "global_load_dwordx4 %4, %9, %12\n\t"                        \
                     "global_load_dwordx4 %5, %9, %12 offset:1024\n\t"            \
                     "global_load_dwordx4 %6, %9, %12 offset:2048\n\t"            \
                     "global_load_dwordx4 %7, %9, %12 offset:3072\n\t"            \
                     "global_load_dwordx4 %8, %10, %13"                           \
                     : "=&v"(TQ[0]), "=&v"(TQ[1]), "=&v"(TQ[2]), "=&v"(TQ[3]),    \
                       "=&v"(TQ[4]), "=&v"(TQ[5]), "=&v"(TQ[6]), "=&v"(TQ[7]),    \
                       "=&v"(EV)                                                  \
                     : "v"(vofft), "v"(voffe), "s"(t0_), "s"(t1_), "s"(eb_)       \
                     : "memory");                                                 \
    }

#define WAIT_TIE(TQ, EV)                                                          \
    asm volatile("s_waitcnt vmcnt(27)"                                            \
                 : "+v"(TQ[0]), "+v"(TQ[1]), "+v"(TQ[2]), "+v"(TQ[3]),            \
                   "+v"(TQ[4]), "+v"(TQ[5]), "+v"(TQ[6]), "+v"(TQ[7]),            \
                   "+v"(EV)                                                       \
                 :: "memory")

#define BPERM_REBUILD(P0, P1)                                                     \
    {                                                                             \
        v4i a0_, a1_;                                                             \
        a0_[0] = __builtin_amdgcn_ds_bpermute(idx0, P0);                          \
        a0_[1] = __builtin_amdgcn_ds_bpermute(idx1, P0);                          \
        a0_[2] = __builtin_amdgcn_ds_bpermute(idx2, P0);                          \
        a0_[3] = __builtin_amdgcn_ds_bpermute(idx3, P0);                          \
        a1_[0] = __builtin_amdgcn_ds_bpermute(idx0, P1);                          \
        a1_[1] = __builtin_amdgcn_ds_bpermute(idx1, P1);                          \
        a1_[2] = __builtin_amdgcn_ds_bpermute(idx2, P1);                          \
        a1_[3] = __builtin_amdgcn_ds_bpermute(idx3, P1);                          \
        af0 = bfrag(a0_); af1 = bfrag(a1_);                                       \
    }

#define MFMA8(TQ)                                                                 \
    v4f z4 = {0.f, 0.f, 0.f, 0.f};                                                \
    v4f d0 = MFMA16(af0, bfrag(TQ[0]), z4);                                       \
    v4f d1 = MFMA16(af0, bfrag(TQ[1]), z4);                                       \
    v4f d2 = MFMA16(af0, bfrag(TQ[2]), z4);                                       \
    v4f d3 = MFMA16(af0, bfrag(TQ[3]), z4);                                       \
    v4f f0 = MFMA16(af1, bfrag(TQ[4]), z4);                                       \
    v4f f1 = MFMA16(af1, bfrag(TQ[5]), z4);                                       \
    v4f f2 = MFMA16(af1, bfrag(TQ[6]), z4);                                       \
    v4f f3 = MFMA16(af1, bfrag(TQ[7]), z4);

// fwd app: MFMA -> +, xEV, x stale inv -> pack -> bpermute -> next A frags
#define COMPUTE_F(TQ, EV)                                                         \
    {                                                                             \
        MFMA8(TQ)                                                                 \
        float ei_ = inv;                                                          \
        float y0 = d0[0] + f0[0], y1 = d1[0] + f1[0];                             \
        float y2 = d2[0] + f2[0], y3 = d3[0] + f3[0];                             \
        zn0 = y0 * EV.x * ei_; zn1 = y1 * EV.y * ei_;                             \
        zn2 = y2 * EV.z * ei_; zn3 = y3 * EV.w * ei_;                             \
        int p0_ = pkh(zn0, zn1), p1_ = pkh(zn2, zn3);                             \
        BPERM_REBUILD(p0_, p1_)                                                   \
        lsacc -= (double)__log2f(ei_);                                            \
        float s_ = (zn0 + zn1) + (zn2 + zn3);                                     \
        DPP16_SUM(s_)                                                             \
        inv = fast_rcp(s_);                                                       \
    }

// bwd app (operator transpose): xEV, x stale inv -> pack -> bpermute -> MFMA(T) -> bare zn
#define COMPUTE_B(TQ, EV)                                                         \
    {                                                                             \
        float ei_ = inv;                                                          \
        float w0 = zn0 * EV.x * ei_, w1 = zn1 * EV.y * ei_;                       \
        float w2 = zn2 * EV.z * ei_, w3 = zn3 * EV.w * ei_;                       \
        int p0_ = pkh(w0, w1), p1_ = pkh(w2, w3);                                 \
        BPERM_REBUILD(p0_, p1_)                                                   \
        MFMA8(TQ)                                                                 \
        zn0 = d0[0] + f0[0]; zn1 = d1[0] + f1[0];                                 \
        zn2 = d2[0] + f2[0]; zn3 = d3[0] + f3[0];                                 \
        lsacc -= (double)__log2f(ei_);                                            \
        float s_ = (w0 + w1) + (w2 + w3);                                         \
        DPP16_SUM(s_)                                                             \
        inv = fast_rcp(s_);                                                       \
    }

// ---------------- prep kernels ----------------
__global__ __launch_bounds__(256) void prep_emit(const float* __restrict__ log_emit) {
    int idx = blockIdx.x * 256 + threadIdx.x;
    int v = idx >> 6;
    int j = idx & 63;
    gEmitT2[v * 64 + (j & 15) * 4 + (j >> 4)] = expf(log_emit[(j + 1) * HMM_V + v]);
}

__global__ __launch_bounds__(64) void prep_small(const float* __restrict__ log_trans,
                                                 const float* __restrict__ log_pi) {
    int j = threadIdx.x;
    for (int i = 0; i < 64; ++i)
        gET[i * 64 + j] = expf(log_trans[(i + 1) * HMM_S + (j + 1)]);
    float s = 0.f;
    for (int i = 0; i < HMM_S; ++i)
        s += expf(log_pi[i]) * expf(log_trans[i * HMM_S + (j + 1)]);
    gArow0[j] = s;
    float tc = log_trans[(j + 1) * HMM_S + 0];
    float mx = tc;
    for (int d = 1; d < 64; d <<= 1) mx = fmaxf(mx, __shfl_xor(mx, d));
    gTcs2[(j & 15) * 4 + (j >> 4)] = expf(tc - mx);
    if (j == 0) gTcmax = mx;
    for (int i = 0; i < 64; ++i) {
        int r, lane, sj;
        frag_pos(i, j, &r, &lane, &sj);
        gP1[(r * 64 + lane) * 8 + sj] = (__fp16)(gET[i * 64 + j] * 1024.0f);
    }
}

__global__ __launch_bounds__(64) void prep_table() {
    __shared__ float ETs[64 * 64];
    __shared__ float ETp[64 * 66];
    __shared__ float ev[64];
    __shared__ __attribute__((aligned(16))) __fp16 stage[4096];  // 8 KB = 512 int4
    const int m = threadIdx.x;
    const int v = blockIdx.x;
    for (int i = 0; i < 64; ++i) ETs[i * 64 + m] = gET[i * 64 + m];
    for (int j = 0; j < 64; ++j) ETp[j * 66 + m] = gET[j * 64 + m];
    ev[m] = gEmitT2[v * 64 + (m & 15) * 4 + (m >> 4)];
    __syncthreads();
    float acc[64];
#pragma unroll
    for (int i = 0; i < 64; ++i) acc[i] = 0.f;
    for (int j = 0; j < 64; ++j) {
        float w = ev[j] * ETp[j * 66 + m];
#pragma unroll
        for (int i = 0; i < 64; ++i) acc[i] = fmaf(ETs[i * 64 + j], w, acc[i]);
    }
    float mx = acc[0];
#pragma unroll
    for (int i = 1; i < 64; ++i) mx = fmaxf(mx, acc[i]);
    for (int d = 1; d < 64; d <<= 1) mx = fmaxf(mx, __shfl_xor(mx, d));
    int e;
    (void)frexpf(mx, &e);
    float sc = exp2f((float)(11 - e));
    if (m == 0) gSlog[v] = (float)(e - 11) * (float)LN2;
    // M-frag image in LDS (acc[i] = M2[i][m] -> position (i, m)), coalesced write
    for (int i = 0; i < 64; ++i) {
        int r, lane, sj;
        frag_pos(i, m, &r, &lane, &sj);
        stage[(r * 64 + lane) * 8 + sj] = (__fp16)(acc[i] * sc);
    }
    __syncthreads();
    {
        int4* dst = (int4*)(gMtab + v * 4096);
        const int4* src = (const int4*)stage;
        for (int k = m; k < 512; k += 64) dst[k] = src[k];  // R10 FIX: 512 int4, was 256
    }
    __syncthreads();
    // T-frag: MT[m][i] = M2[i][m] = acc[i] -> position (m, i)
    for (int i = 0; i < 64; ++i) {
        int r, lane, sj;
        frag_pos(m, i, &r, &lane, &sj);
        stage[(r * 64 + lane) * 8 + sj] = (__fp16)(acc[i] * sc);
    }
    __syncthreads();
    {
        int4* dst = (int4*)(gMtabT + v * 4096);
        const int4* src = (const int4*)stage;
        for (int k = m; k < 512; k += 64) dst[k] = src[k];  // R10 FIX: 512 int4, was 256
    }
}

// ---------------- split-scan kernel: 256 blocks = 128 batches x {fwd,bwd} ----------------
__global__ __launch_bounds__(64, 1) void hmm_scan(const int* __restrict__ obvs) {
    __shared__ __attribute__((aligned(16))) ushort4 obs4[1040];  // word guards included
    __shared__ float a0lds[64];
    const int bid = blockIdx.x;
    const int b = bid >> 1;
    const bool isf = (bid & 1) == 0;
    const int lane = threadIdx.x;
    const uint* view = (const uint*)obs4;  // uint word = (obs[2a], obs[2a+1])

    // ---- stage this direction's half of obs + separable slog sum ----
    float slsum = 0.f;
    {
        const int4* og = (const int4*)(obvs + b * HMM_T);
        if (isf) {
            for (int it = lane; it < 1024; it += 64) {
                int4 o = og[it];
                obs4[it] = make_ushort4((unsigned short)o.x, (unsigned short)o.y,
                                        (unsigned short)o.z, (unsigned short)o.w);
                slsum += (it != 0 ? gSlog[o.x] : 0.f) + gSlog[o.z];  // apps 2it, 2it+1
            }
            if (lane < 8) obs4[1024 + lane] = make_ushort4(0, 0, 0, 0);  // words 2048..2063
        } else {
            for (int it = 1024 + lane; it < 2048; it += 64) {
                int4 o = og[it];
                obs4[it - 1020] = make_ushort4((unsigned short)o.x, (unsigned short)o.y,
                                               (unsigned short)o.z, (unsigned short)o.w);
                slsum += gSlog[o.x] + gSlog[o.z];  // apps 2it, 2it+1 in [2048,4095]
            }
            if (lane < 4) obs4[lane] = make_ushort4(0, 0, 0, 0);  // words 2040..2047 guard
        }
    }

    const int vofft = lane * 16;
    const int voffe = (lane & 15) * 16;
    const int idx0 = (lane >> 4) * 16;
    const int idx1 = idx0 + 4, idx2 = idx0 + 8, idx3 = idx0 + 12;

    double lsacc;
    float zn0, zn1, zn2, zn3;
    float inv = 1.0f;
    h8 af0, af1;

    v4i qa[8], qb[8], qc[8], qd[8];
    v4f ea, eb, ec, ed;

    if (isf) {
        // ---- fwd init: alpha0 (exact, incl bookend), normalized ----
        int o0 = obvs[b * HMM_T];
        float a0 = gArow0[lane] * gEmitT2[o0 * 64 + (lane & 15) * 4 + (lane >> 4)];
        float s0 = a0;
#pragma unroll
        for (int d = 1; d < 64; d <<= 1) s0 += __shfl_xor(s0, d);
        a0lds[lane] = a0 / s0;
        __syncthreads();
        lsacc = (double)__log2f(s0) - 10.0;  // -10 repays gP1's 2^10 scale
        {
            const int g4 = (lane >> 4) * 4;
            v4i a0_, a1_;
#pragma unroll
            for (int ri = 0; ri < 4; ++ri) {
                a0_[ri] = pkh(a0lds[g4 + ri], a0lds[16 + g4 + ri]);
                a1_[ri] = pkh(a0lds[32 + g4 + ri], a0lds[48 + g4 + ri]);
            }
            af0 = bfrag(a0_);
            af1 = bfrag(a1_);
        }
        zn0 = zn1 = zn2 = zn3 = 0.f;

        // ---- prologue: apps 0..3 ----
        ISSUE_APP(qa, ea, view[0] & 0xFFFF0000u, gP1)
        ISSUE_APP(qb, eb, view[1], gMtab)
        ISSUE_APP(qc, ec, view[2], gMtab)
        ISSUE_APP(qd, ed, view[3], gMtab)
        uint o0p = view[4], o1p = view[5], o2p = view[6], o3p = view[7];

        for (int g = 0; g < 512; ++g) {
            const int base = 4 * g;
            WAIT_TIE(qa, ea);
            COMPUTE_F(qa, ea)
            ISSUE_APP(qa, ea, o0p, gMtab)
            o0p = view[base + 8];
            WAIT_TIE(qb, eb);
            COMPUTE_F(qb, eb)
            ISSUE_APP(qb, eb, o1p, gMtab)
            o1p = view[base + 9];
            WAIT_TIE(qc, ec);
            COMPUTE_F(qc, ec)
            ISSUE_APP(qc, ec, o2p, gMtab)
            o2p = view[base + 10];
            WAIT_TIE(qd, ed);
            COMPUTE_F(qd, ed)
            ISSUE_APP(qd, ed, o3p, gMtab)
            o3p = view[base + 11];
        }
        asm volatile("s_waitcnt vmcnt(0)" ::: "memory");

#pragma unroll
        for (int d = 1; d < 64; d <<= 1) slsum += __shfl_xor(slsum, d);
        if (lane < 16) {
            float* fb = gF + b * 64 + lane * 4;
            fb[0] = zn0; fb[1] = zn1; fb[2] = zn2; fb[3] = zn3;
        }
        if (lane == 0) gLF[b] = (double)slsum + lsacc * LN2;
    } else {
        // ---- bwd init: g = tau * 2^10 (repaid in lsacc) ----
        __syncthreads();  // staging visible
        const float4 tc4 = *(const float4*)(gTcs2 + (lane & 15) * 4);
        zn0 = tc4.x * 1024.0f; zn1 = tc4.y * 1024.0f;
        zn2 = tc4.z * 1024.0f; zn3 = tc4.w * 1024.0f;
        lsacc = -10.0;
        // view index for word w is (w - 2040); guards cover 2040..2047
#define VB(W) view[(W) - 2040]
        // ---- prologue: apps 4095..4092 ----
        ISSUE_APP(qa, ea, VB(4095), gMtabT)
        ISSUE_APP(qb, eb, VB(4094), gMtabT)
        ISSUE_APP(qc, ec, VB(4093), gMtabT)
        ISSUE_APP(qd, ed, VB(4092), gMtabT)
        uint o0p = VB(4091), o1p = VB(4090), o2p = VB(4089), o3p = VB(4088);

        for (int g = 0; g < 512; ++g) {
            const int base = 4095 - 4 * g;
            WAIT_TIE(qa, ea);
            COMPUTE_B(qa, ea)
            ISSUE_APP(qa, ea, o0p, gMtabT)
            o0p = VB(base - 8);
            WAIT_TIE(qb, eb);
            COMPUTE_B(qb, eb)
            ISSUE_APP(qb, eb, o1p, gMtabT)
            o1p = VB(base - 9);
            WAIT_TIE(qc, ec);
            COMPUTE_B(qc, ec)
            ISSUE_APP(qc, ec, o2p, gMtabT)
            o2p = VB(base - 10);
            WAIT_TIE(qd, ed);
            COMPUTE_B(qd, ed)
            ISSUE_APP(qd, ed, o3p, gMtabT)
            o3p = VB(base - 11);
        }
        asm volatile("s_waitcnt vmcnt(0)" ::: "memory");

#pragma unroll
        for (int d = 1; d < 64; d <<= 1) slsum += __shfl_xor(slsum, d);
        if (lane < 16) {
            float* gb = gG + b * 64 + lane * 4;
            gb[0] = zn0; gb[1] = zn1; gb[2] = zn2; gb[3] = zn3;
        }
        if (lane == 0) gLB[b] = (double)slsum + lsacc * LN2;
#undef VB
    }
}

// ---------------- combine: out[b] = log(f.g) + logs + tcmax ----------------
__global__ __launch_bounds__(64) void hmm_combine(float* __restrict__ out) {
    const int b = blockIdx.x;
    const int lane = threadIdx.x;
    float pr = gF[b * 64 + lane] * gG[b * 64 + lane];
#pragma unroll
    for (int d = 1; d < 64; d <<= 1) pr += __shfl_xor(pr, d);
    if (lane == 0)
        out[b] = (float)(gLF[b] + gLB[b] + (double)gTcmax + (double)__logf(pr));
}

// ---------------- launch ----------------
extern "C" void kernel_launch(void* const* d_in, const int* in_sizes, int n_in,
                              void* d_out, int out_size, void* d_ws, size_t ws_size,
                              hipStream_t stream) {
    const float* log_trans = (const float*)d_in[0];  // 65*65
    const float* log_emit  = (const float*)d_in[1];  // 65*1024
    const float* log_pi    = (const float*)d_in[2];  // 65
    const int*   obvs      = (const int*)d_in[3];    // 128*8192
    float* out = (float*)d_out;

    prep_emit<<<256, 256, 0, stream>>>(log_emit);
    prep_small<<<1, 64, 0, stream>>>(log_trans, log_pi);
    prep_table<<<1024, 64, 0, stream>>>();
    hmm_scan<<<2 * HMM_B, 64, 0, stream>>>(obvs);
    hmm_combine<<<HMM_B, 64, 0, stream>>>(out);
}

// Round 13
// 508.683 us; speedup vs baseline: 4.2812x; 1.0649x over previous
//
#include <hip/hip_runtime.h>
#include <hip/hip_bf16.h>
#include <stdint.h>

// HMM batched forward, B=128, T=8192, S=65 (state 0 = bookend dead after init), V=1024.
//
// R13 = R10's proven scan (423 us, absmax 256) restored VERBATIM after the
// R11/R12 lambda-relabel scheme failed twice on an unverifiable operand-layout
// assumption (A vs B f16 slot mappings need not be symmetric; R7/R10 are
// mapping-invariant because they label both operands themselves).
// New this round: prep_table rewritten 64 -> 256 threads/block. The old version
// issued 4096 ds_read_b32 per thread in the fused-matrix FMA loop (~40+ us of
// pure LDS-issue across the grid) plus 128 scattered ds_write_b16/thread.
// Wave-per-16-row-segment cuts both 4x; FMA order per (i,m) unchanged ->
// bitwise-identical tables.
//
// Design (R10): bidirectional split. L = tau^T (M_4095..M_2048)(M_2047..M_0) a0
// = g . f; fwd chain (apps 0..2047) and bwd chain (apps 4095..2048, table =
// M^T, emission applied before matvec). 256 blocks = 128 batches x {fwd,bwd}.
// Per-app: asm global_load_dwordx4 depth-4 ring + s_waitcnt vmcnt(27),
// replicated-A MFMA (independent K-halves), stale-inv renorm, ds_bpermute
// A-rebuild.

#define HMM_B 128
#define HMM_T 8192
#define HMM_S 65
#define HMM_V 1024
#define LN2 0.6931471805599453

typedef _Float16 h8 __attribute__((ext_vector_type(8)));
typedef int    v4i __attribute__((ext_vector_type(4)));
typedef float  v4f __attribute__((ext_vector_type(4)));
typedef unsigned int uint;

// ---------------- device-global tables ----------------
__device__ __attribute__((aligned(16))) __fp16 gMtab[HMM_V * 4096];   // fused 2-step, B-frag
__device__ __attribute__((aligned(16))) __fp16 gMtabT[HMM_V * 4096];  // transposed, B-frag
__device__ __attribute__((aligned(16))) __fp16 gP1[4096];             // app-0 1-step (ET*2^10)
__device__ __attribute__((aligned(16))) float  gEmitT2[HMM_V * 64];   // [v][c*4+u] = e_v[16u+c]
__device__ float gSlog[HMM_V];
__device__ float gET[64 * 64];
__device__ __attribute__((aligned(16))) float gArow0[64];
__device__ __attribute__((aligned(16))) float gTcs2[64];  // [c*4+u] = exp(tcol[16u+c]-tcmax)
__device__ float gTcmax;
// split-scan handoff
__device__ __attribute__((aligned(16))) float gF[HMM_B * 64];
__device__ __attribute__((aligned(16))) float gG[HMM_B * 64];
__device__ double gLF[HMM_B];
__device__ double gLB[HMM_B];

// frag-position: value X[i][n] (input row i, output col n) -> (r, lane, slot j)
__device__ __forceinline__ void frag_pos(int i, int n, int* r, int* lane, int* j) {
    int t = i >> 5, up = (i >> 4) & 1, g = (i & 15) >> 2, q = i & 3;
    *r = t * 4 + (n >> 4);
    *lane = g * 16 + (n & 15);
    *j = 2 * q + up;
}

// ---------------- helpers ----------------
template <int CTRL>
__device__ __forceinline__ float dpp_add(float x) {
    return x + __int_as_float(__builtin_amdgcn_update_dpp(
                   0, __float_as_int(x), CTRL, 0xF, 0xF, true));
}
#define DPP16_SUM(S)            \
    S = dpp_add<0xB1>(S);       \
    S = dpp_add<0x4E>(S);       \
    S = dpp_add<0x141>(S);      \
    S = dpp_add<0x128>(S);

__device__ __forceinline__ float fast_rcp(float x) {
#if __has_builtin(__builtin_amdgcn_rcpf)
    return __builtin_amdgcn_rcpf(x);
#else
    return 1.0f / x;
#endif
}

__device__ __forceinline__ h8 bfrag(v4i q) { return __builtin_bit_cast(h8, q); }
__device__ __forceinline__ int pkh(float a, float b) {
    return __builtin_bit_cast(int, __builtin_amdgcn_cvt_pkrtz(a, b));
}

#define MFMA16(A, B, C) __builtin_amdgcn_mfma_f32_16x16x32_f16((A), (B), (C), 0, 0, 0)

#define ISSUE_APP(TQ, EV, W, TBASE)                                               \
    {                                                                             \
        uint w_ = (W);                                                            \
        uint u_ = (uint)__builtin_amdgcn_readfirstlane((int)w_);                  \
        const __fp16* t0_ = (TBASE) + (size_t)(u_ & 0xFFFFu) * 4096u;             \
        const __fp16* t1_ = t0_ + 2048;                                           \
        const float* eb_ = gEmitT2 + (size_t)(u_ >> 16) * 64u;                    \
        asm volatile("global_load_dwordx4 %0, %9, %11\n\t"                        \
                     "global_load_dwordx4 %1, %9, %11 offset:1024\n\t"            \
                     "global_load_dwordx4 %2, %9, %11 offset:2048\n\t"            \
                     "global_load_dwordx4 %3, %9, %11 offset:3072\n\t"            \
                     "global_load_dwordx4 %4, %9, %12\n\t"                        \
                     "global_load_dwordx4 %5, %9, %12 offset:1024\n\t"            \
                     "global_load_dwordx4 %6, %9, %12 offset:2048\n\t"            \
                     "global_load_dwordx4 %7, %9, %12 offset:3072\n\t"            \
                     "global_load_dwordx4 %8, %10, %13"                           \
                     : "=&v"(TQ[0]), "=&v"(TQ[1]), "=&v"(TQ[2]), "=&v"(TQ[3]),    \
                       "=&v"(TQ[4]), "=&v"(TQ[5]), "=&v"(TQ[6]), "=&v"(TQ[7]),    \
                       "=&v"(EV)                                                  \
                     : "v"(vofft), "v"(voffe), "s"(t0_), "s"(t1_), "s"(eb_)       \
                     : "memory");                                                 \
    }

#define WAIT_TIE(TQ, EV)                                                          \
    asm volatile("s_waitcnt vmcnt(27)"                                            \
                 : "+v"(TQ[0]), "+v"(TQ[1]), "+v"(TQ[2]), "+v"(TQ[3]),            \
                   "+v"(TQ[4]), "+v"(TQ[5]), "+v"(TQ[6]), "+v"(TQ[7]),            \
                   "+v"(EV)                                                       \
                 :: "memory")

#define BPERM_REBUILD(P0, P1)                                                     \
    {                                                                             \
        v4i a0_, a1_;                                                             \
        a0_[0] = __builtin_amdgcn_ds_bpermute(idx0, P0);                          \
        a0_[1] = __builtin_amdgcn_ds_bpermute(idx1, P0);                          \
        a0_[2] = __builtin_amdgcn_ds_bpermute(idx2, P0);                          \
        a0_[3] = __builtin_amdgcn_ds_bpermute(idx3, P0);                          \
        a1_[0] = __builtin_amdgcn_ds_bpermute(idx0, P1);                          \
        a1_[1] = __builtin_amdgcn_ds_bpermute(idx1, P1);                          \
        a1_[2] = __builtin_amdgcn_ds_bpermute(idx2, P1);                          \
        a1_[3] = __builtin_amdgcn_ds_bpermute(idx3, P1);                          \
        af0 = bfrag(a0_); af1 = bfrag(a1_);                                       \
    }

#define MFMA8(TQ)                                                                 \
    v4f z4 = {0.f, 0.f, 0.f, 0.f};                                                \
    v4f d0 = MFMA16(af0, bfrag(TQ[0]), z4);                                       \
    v4f d1 = MFMA16(af0, bfrag(TQ[1]), z4);                                       \
    v4f d2 = MFMA16(af0, bfrag(TQ[2]), z4);                                       \
    v4f d3 = MFMA16(af0, bfrag(TQ[3]), z4);                                       \
    v4f f0 = MFMA16(af1, bfrag(TQ[4]), z4);                                       \
    v4f f1 = MFMA16(af1, bfrag(TQ[5]), z4);                                       \
    v4f f2 = MFMA16(af1, bfrag(TQ[6]), z4);                                       \
    v4f f3 = MFMA16(af1, bfrag(TQ[7]), z4);

// fwd app: MFMA -> +, xEV, x stale inv -> pack -> bpermute -> next A frags
#define COMPUTE_F(TQ, EV)                                                         \
    {                                                                             \
        MFMA8(TQ)                                                                 \
        float ei_ = inv;                                                          \
        float y0 = d0[0] + f0[0], y1 = d1[0] + f1[0];                             \
        float y2 = d2[0] + f2[0], y3 = d3[0] + f3[0];                             \
        zn0 = y0 * EV.x * ei_; zn1 = y1 * EV.y * ei_;                             \
        zn2 = y2 * EV.z * ei_; zn3 = y3 * EV.w * ei_;                             \
        int p0_ = pkh(zn0, zn1), p1_ = pkh(zn2, zn3);                             \
        BPERM_REBUILD(p0_, p1_)                                                   \
        lsacc -= (double)__log2f(ei_);                                            \
        float s_ = (zn0 + zn1) + (zn2 + zn3);                                     \
        DPP16_SUM(s_)                                                             \
        inv = fast_rcp(s_);                                                       \
    }

// bwd app (operator transpose): xEV, x stale inv -> pack -> bpermute -> MFMA(T) -> bare zn
#define COMPUTE_B(TQ, EV)                                                         \
    {                                                                             \
        float ei_ = inv;                                                          \
        float w0 = zn0 * EV.x * ei_, w1 = zn1 * EV.y * ei_;                       \
        float w2 = zn2 * EV.z * ei_, w3 = zn3 * EV.w * ei_;                       \
        int p0_ = pkh(w0, w1), p1_ = pkh(w2, w3);                                 \
        BPERM_REBUILD(p0_, p1_)                                                   \
        MFMA8(TQ)                                                                 \
        zn0 = d0[0] + f0[0]; zn1 = d1[0] + f1[0];                                 \
        zn2 = d2[0] + f2[0]; zn3 = d3[0] + f3[0];                                 \
        lsacc -= (double)__log2f(ei_);                                            \
        float s_ = (w0 + w1) + (w2 + w3);                                         \
        DPP16_SUM(s_)                                                             \
        inv = fast_rcp(s_);                                                       \
    }

// ---------------- prep kernels ----------------
__global__ __launch_bounds__(256) void prep_emit(const float* __restrict__ log_emit) {
    int idx = blockIdx.x * 256 + threadIdx.x;
    int v = idx >> 6;
    int j = idx & 63;
    gEmitT2[v * 64 + (j & 15) * 4 + (j >> 4)] = expf(log_emit[(j + 1) * HMM_V + v]);
}

__global__ __launch_bounds__(64) void prep_small(const float* __restrict__ log_trans,
                                                 const float* __restrict__ log_pi) {
    int j = threadIdx.x;
    for (int i = 0; i < 64; ++i)
        gET[i * 64 + j] = expf(log_trans[(i + 1) * HMM_S + (j + 1)]);
    float s = 0.f;
    for (int i = 0; i < HMM_S; ++i)
        s += expf(log_pi[i]) * expf(log_trans[i * HMM_S + (j + 1)]);
    gArow0[j] = s;
    float tc = log_trans[(j + 1) * HMM_S + 0];
    float mx = tc;
    for (int d = 1; d < 64; d <<= 1) mx = fmaxf(mx, __shfl_xor(mx, d));
    gTcs2[(j & 15) * 4 + (j >> 4)] = expf(tc - mx);
    if (j == 0) gTcmax = mx;
    for (int i = 0; i < 64; ++i) {
        int r, lane, sj;
        frag_pos(i, j, &r, &lane, &sj);
        gP1[(r * 64 + lane) * 8 + sj] = (__fp16)(gET[i * 64 + j] * 1024.0f);
    }
}

// 256 threads: wave seg = t>>6 owns i-rows [16seg, 16seg+16); m = t&63.
// FMA order per (i, m) identical to the 64-thread version -> bitwise-same tables.
__global__ __launch_bounds__(256) void prep_table() {
    __shared__ float ETs[64 * 64];
    __shared__ float ETp[64 * 66];
    __shared__ float ev[64];
    __shared__ float wmax[4];
    __shared__ __attribute__((aligned(16))) __fp16 stage[4096];  // 8 KB = 512 int4
    const int t = threadIdx.x;
    const int m = t & 63;
    const int seg = t >> 6;
    const int i0 = seg * 16;
    const int v = blockIdx.x;
    for (int i = i0; i < i0 + 16; ++i) ETs[i * 64 + m] = gET[i * 64 + m];
    for (int j = i0; j < i0 + 16; ++j) ETp[j * 66 + m] = gET[j * 64 + m];
    if (t < 64) ev[t] = gEmitT2[v * 64 + (t & 15) * 4 + (t >> 4)];
    __syncthreads();
    float acc[16];  // acc[q] = M2[i0+q][m]
#pragma unroll
    for (int q = 0; q < 16; ++q) acc[q] = 0.f;
    for (int j = 0; j < 64; ++j) {
        float w = ev[j] * ETp[j * 66 + m];
#pragma unroll
        for (int q = 0; q < 16; ++q) acc[q] = fmaf(ETs[(i0 + q) * 64 + j], w, acc[q]);
    }
    float mx = acc[0];
#pragma unroll
    for (int q = 1; q < 16; ++q) mx = fmaxf(mx, acc[q]);
    for (int d = 1; d < 64; d <<= 1) mx = fmaxf(mx, __shfl_xor(mx, d));
    if (m == 0) wmax[seg] = mx;
    __syncthreads();
    mx = fmaxf(fmaxf(wmax[0], wmax[1]), fmaxf(wmax[2], wmax[3]));
    int e;
    (void)frexpf(mx, &e);
    float sc = exp2f((float)(11 - e));
    if (t == 0) gSlog[v] = (float)(e - 11) * (float)LN2;
    // FWD B-frag image: value M2[i][m] at frag_pos(i, m)
    for (int q = 0; q < 16; ++q) {
        int i = i0 + q;
        int r, lane, sj;
        frag_pos(i, m, &r, &lane, &sj);
        stage[(r * 64 + lane) * 8 + sj] = (__fp16)(acc[q] * sc);
    }
    __syncthreads();
    {
        int4* dst = (int4*)(gMtab + v * 4096);
        const int4* src = (const int4*)stage;
        for (int k = t; k < 512; k += 256) dst[k] = src[k];
    }
    __syncthreads();
    // BWD (transposed) B-frag image: value M2[i][m] at frag_pos(m, i)
    for (int q = 0; q < 16; ++q) {
        int i = i0 + q;
        int r, lane, sj;
        frag_pos(m, i, &r, &lane, &sj);
        stage[(r * 64 + lane) * 8 + sj] = (__fp16)(acc[q] * sc);
    }
    __syncthreads();
    {
        int4* dst = (int4*)(gMtabT + v * 4096);
        const int4* src = (const int4*)stage;
        for (int k = t; k < 512; k += 256) dst[k] = src[k];
    }
}

// ---------------- split-scan kernel: 256 blocks = 128 batches x {fwd,bwd} ----------------
__global__ __launch_bounds__(64, 1) void hmm_scan(const int* __restrict__ obvs) {
    __shared__ __attribute__((aligned(16))) ushort4 obs4[1040];  // word guards included
    __shared__ float a0lds[64];
    const int bid = blockIdx.x;
    const int b = bid >> 1;
    const bool isf = (bid & 1) == 0;
    const int lane = threadIdx.x;
    const uint* view = (const uint*)obs4;  // uint word = (obs[2a], obs[2a+1])

    // ---- stage this direction's half of obs + separable slog sum ----
    float slsum = 0.f;
    {
        const int4* og = (const int4*)(obvs + b * HMM_T);
        if (isf) {
            for (int it = lane; it < 1024; it += 64) {
                int4 o = og[it];
                obs4[it] = make_ushort4((unsigned short)o.x, (unsigned short)o.y,
                                        (unsigned short)o.z, (unsigned short)o.w);
                slsum += (it != 0 ? gSlog[o.x] : 0.f) + gSlog[o.z];  // apps 2it, 2it+1
            }
            if (lane < 8) obs4[1024 + lane] = make_ushort4(0, 0, 0, 0);  // words 2048..2063
        } else {
            for (int it = 1024 + lane; it < 2048; it += 64) {
                int4 o = og[it];
                obs4[it - 1020] = make_ushort4((unsigned short)o.x, (unsigned short)o.y,
                                               (unsigned short)o.z, (unsigned short)o.w);
                slsum += gSlog[o.x] + gSlog[o.z];  // apps 2it, 2it+1 in [2048,4095]
            }
            if (lane < 4) obs4[lane] = make_ushort4(0, 0, 0, 0);  // words 2040..2047 guard
        }
    }

    const int vofft = lane * 16;
    const int voffe = (lane & 15) * 16;
    const int idx0 = (lane >> 4) * 16;
    const int idx1 = idx0 + 4, idx2 = idx0 + 8, idx3 = idx0 + 12;

    double lsacc;
    float zn0, zn1, zn2, zn3;
    float inv = 1.0f;
    h8 af0, af1;

    v4i qa[8], qb[8], qc[8], qd[8];
    v4f ea, eb, ec, ed;

    if (isf) {
        // ---- fwd init: alpha0 (exact, incl bookend), normalized ----
        int o0 = obvs[b * HMM_T];
        float a0 = gArow0[lane] * gEmitT2[o0 * 64 + (lane & 15) * 4 + (lane >> 4)];
        float s0 = a0;
#pragma unroll
        for (int d = 1; d < 64; d <<= 1) s0 += __shfl_xor(s0, d);
        a0lds[lane] = a0 / s0;
        __syncthreads();
        lsacc = (double)__log2f(s0) - 10.0;  // -10 repays gP1's 2^10 scale
        {
            const int g4 = (lane >> 4) * 4;
            v4i a0_, a1_;
#pragma unroll
            for (int ri = 0; ri < 4; ++ri) {
                a0_[ri] = pkh(a0lds[g4 + ri], a0lds[16 + g4 + ri]);
                a1_[ri] = pkh(a0lds[32 + g4 + ri], a0lds[48 + g4 + ri]);
            }
            af0 = bfrag(a0_);
            af1 = bfrag(a1_);
        }
        zn0 = zn1 = zn2 = zn3 = 0.f;

        // ---- prologue: apps 0..3 ----
        ISSUE_APP(qa, ea, view[0] & 0xFFFF0000u, gP1)
        ISSUE_APP(qb, eb, view[1], gMtab)
        ISSUE_APP(qc, ec, view[2], gMtab)
        ISSUE_APP(qd, ed, view[3], gMtab)
        uint o0p = view[4], o1p = view[5], o2p = view[6], o3p = view[7];

        for (int g = 0; g < 512; ++g) {
            const int base = 4 * g;
            WAIT_TIE(qa, ea);
            COMPUTE_F(qa, ea)
            ISSUE_APP(qa, ea, o0p, gMtab)
            o0p = view[base + 8];
            WAIT_TIE(qb, eb);
            COMPUTE_F(qb, eb)
            ISSUE_APP(qb, eb, o1p, gMtab)
            o1p = view[base + 9];
            WAIT_TIE(qc, ec);
            COMPUTE_F(qc, ec)
            ISSUE_APP(qc, ec, o2p, gMtab)
            o2p = view[base + 10];
            WAIT_TIE(qd, ed);
            COMPUTE_F(qd, ed)
            ISSUE_APP(qd, ed, o3p, gMtab)
            o3p = view[base + 11];
        }
        asm volatile("s_waitcnt vmcnt(0)" ::: "memory");

#pragma unroll
        for (int d = 1; d < 64; d <<= 1) slsum += __shfl_xor(slsum, d);
        if (lane < 16) {
            float* fb = gF + b * 64 + lane * 4;
            fb[0] = zn0; fb[1] = zn1; fb[2] = zn2; fb[3] = zn3;
        }
        if (lane == 0) gLF[b] = (double)slsum + lsacc * LN2;
    } else {
        // ---- bwd init: g = tau * 2^10 (repaid in lsacc) ----
        __syncthreads();  // staging visible
        const float4 tc4 = *(const float4*)(gTcs2 + (lane & 15) * 4);
        zn0 = tc4.x * 1024.0f; zn1 = tc4.y * 1024.0f;
        zn2 = tc4.z * 1024.0f; zn3 = tc4.w * 1024.0f;
        lsacc = -10.0;
        // view index for word w is (w - 2040); guards cover 2040..2047
#define VB(W) view[(W) - 2040]
        // ---- prologue: apps 4095..4092 ----
        ISSUE_APP(qa, ea, VB(4095), gMtabT)
        ISSUE_APP(qb, eb, VB(4094), gMtabT)
        ISSUE_APP(qc, ec, VB(4093), gMtabT)
        ISSUE_APP(qd, ed, VB(4092), gMtabT)
        uint o0p = VB(4091), o1p = VB(4090), o2p = VB(4089), o3p = VB(4088);

        for (int g = 0; g < 512; ++g) {
            const int base = 4095 - 4 * g;
            WAIT_TIE(qa, ea);
            COMPUTE_B(qa, ea)
            ISSUE_APP(qa, ea, o0p, gMtabT)
            o0p = VB(base - 8);
            WAIT_TIE(qb, eb);
            COMPUTE_B(qb, eb)
            ISSUE_APP(qb, eb, o1p, gMtabT)
            o1p = VB(base - 9);
            WAIT_TIE(qc, ec);
            COMPUTE_B(qc, ec)
            ISSUE_APP(qc, ec, o2p, gMtabT)
            o2p = VB(base - 10);
            WAIT_TIE(qd, ed);
            COMPUTE_B(qd, ed)
            ISSUE_APP(qd, ed, o3p, gMtabT)
            o3p = VB(base - 11);
        }
        asm volatile("s_waitcnt vmcnt(0)" ::: "memory");

#pragma unroll
        for (int d = 1; d < 64; d <<= 1) slsum += __shfl_xor(slsum, d);
        if (lane < 16) {
            float* gb = gG + b * 64 + lane * 4;
            gb[0] = zn0; gb[1] = zn1; gb[2] = zn2; gb[3] = zn3;
        }
        if (lane == 0) gLB[b] = (double)slsum + lsacc * LN2;
#undef VB
    }
}

// ---------------- combine: out[b] = log(f.g) + logs + tcmax ----------------
__global__ __launch_bounds__(64) void hmm_combine(float* __restrict__ out) {
    const int b = blockIdx.x;
    const int lane = threadIdx.x;
    float pr = gF[b * 64 + lane] * gG[b * 64 + lane];
#pragma unroll
    for (int d = 1; d < 64; d <<= 1) pr += __shfl_xor(pr, d);
    if (lane == 0)
        out[b] = (float)(gLF[b] + gLB[b] + (double)gTcmax + (double)__logf(pr));
}

// ---------------- launch ----------------
extern "C" void kernel_launch(void* const* d_in, const int* in_sizes, int n_in,
                              void* d_out, int out_size, void* d_ws, size_t ws_size,
                              hipStream_t stream) {
    const float* log_trans = (const float*)d_in[0];  // 65*65
    const float* log_emit  = (const float*)d_in[1];  // 65*1024
    const float* log_pi    = (const float*)d_in[2];  // 65
    const int*   obvs      = (const int*)d_in[3];    // 128*8192
    float* out = (float*)d_out;

    prep_emit<<<256, 256, 0, stream>>>(log_emit);
    prep_small<<<1, 64, 0, stream>>>(log_trans, log_pi);
    prep_table<<<1024, 256, 0, stream>>>();
    hmm_scan<<<2 * HMM_B, 64, 0, stream>>>(obvs);
    hmm_combine<<<HMM_B, 64, 0, stream>>>(out);
}